// Round 5
// baseline (609.954 us; speedup 1.0000x reference)
//
#include <hip/hip_runtime.h>
#include <math.h>

#define L_TOT 36864
#define BN_EPS 1e-5f
#define PCH 45000   // padded channel stride: 18*50*50

typedef __attribute__((ext_vector_type(8))) short bf16x8;
typedef __attribute__((ext_vector_type(4))) float f32x4;

__device__ __forceinline__ float fsigmoid(float x){ return 1.f/(1.f+__expf(-x)); }
__device__ __forceinline__ float fsoftplus(float x){
  float e = __expf(x);
  return (x>20.f)? x : __logf(1.f+e);
}
__device__ __forceinline__ unsigned short f2bf(float x){
  union { float f; unsigned u; } cv; cv.f = x;
  unsigned r = (cv.u + 0x7FFFu + ((cv.u>>16)&1u)) >> 16;
  return (unsigned short)r;
}
__host__ __device__ constexpr int off3c(int r){
  return (r>=27) ? 0 : ((r/9)-1)*2500 + (((r%9)/3)-1)*50 + ((r%3)-1);
}

// ---- invalidate-free grid sync ---------------------------------------------------
// Writers publish via RELEASE fetch_add (emits L2 writeback of dirty lines -> L3;
// proven by rounds 3/4 passing with acquire-readers). Readers poll RELAXED (no
// invalidate!) and then read ONLY the cross-block data via relaxed agent-scope
// 64-bit atomic loads (bypass stale local L2, hit the coherence point). All other
// data (weights/residual) keeps warm L1/L2 - no cache pollution.
__device__ __forceinline__ void bar_signal(unsigned* c){
  __syncthreads();   // drains this block's global stores (vmcnt0) before release
  if (threadIdx.x == 0)
    __hip_atomic_fetch_add(c, 1u, __ATOMIC_RELEASE, __HIP_MEMORY_SCOPE_AGENT);
}
__device__ __forceinline__ void bar_wait(unsigned* c, unsigned target){
  if (threadIdx.x == 0){
    unsigned spins = 0;
    while (__hip_atomic_load(c, __ATOMIC_RELAXED, __HIP_MEMORY_SCOPE_AGENT) < target){
      __builtin_amdgcn_s_sleep(4);
      if (++spins > (1u<<26)) break;   // failsafe: clean fail instead of hang
    }
  }
  __syncthreads();
}
__device__ __forceinline__ float2 ld_f2_coh(const float* p){
  unsigned long long v = __hip_atomic_load((const unsigned long long*)p,
                          __ATOMIC_RELAXED, __HIP_MEMORY_SCOPE_AGENT);
  union { unsigned long long u; float2 f; } cv; cv.u = v; return cv.f;
}

// ---------------- setup: pack conv weights + zero bf16 halo buffer/stats/barriers -
__global__ void k_setup(const float* __restrict__ w1, unsigned short* __restrict__ wA1,
                        const float* __restrict__ w2, unsigned short* __restrict__ wA2,
                        float* __restrict__ stats, unsigned* __restrict__ bar,
                        float* __restrict__ bfz) {
  int b = blockIdx.x, tid = threadIdx.x;
  int idx = b*256 + tid;
  if (idx < 16*PCH) bfz[idx] = 0.f;     // zero all 32 bf16 channels (as 32-bit words)
  if (b < 4){
    int k = b*256 + tid;
    if (k < 864){
      int ic = k & 31, r = k >> 5;
      for (int m=0;m<16;m++){
        float v = (r < 27) ? w1[m*32*27 + ic*27 + r] : 0.f;
        wA1[(((k>>3)*16) + m)*8 + (k&7)] = f2bf(v);
      }
    }
  } else if (b < 6){
    int k = (b-4)*256 + tid;
    if (k < 448){
      int ic = k & 15, r = k >> 4;
      for (int m=0;m<16;m++){
        float v = (r < 27) ? w2[m*16*27 + ic*27 + r] : 0.f;
        wA2[(((k>>3)*16) + m)*8 + (k&7)] = f2bf(v);
      }
    }
  } else if (b == 6){
    if (tid < 64) stats[tid] = 0.f;
    if (tid >= 64 && tid < 68) bar[tid-64] = 0u;   // re-zero barrier counters per iter
  }
}

struct MambaArgs {
  const float *x0, *x1, *bstats, *bg, *bbp;
  const float *lnw, *lnb, *inw, *cw, *cb, *xpw, *dtw, *dtb, *Alog, *Dp, *ow;
  const float *r0src, *r1src;
  float *aggA, *aggB, *carry;
  unsigned *bar0, *bar1;
  unsigned short* rp;
};

// =================================================================================
// k_mamba: ONE kernel for the whole mamba block (persistent, invalidate-free sync;
// all 768 blocks co-resident: LDS 48.2KB -> 3 blocks/CU, VGPR capped by bounds).
// =================================================================================
template<int DIM, int DI, int DTR, bool DOBN, int RES>
__global__ __launch_bounds__(256,3) void k_mamba(MambaArgs a)
{
  constexpr int TCH  = 48;
  constexpr int NCHUNK = 768;
  constexpr int ROWS = DTR + 32;
  constexpr int NSH  = 256/DI;        // threads per d-channel in scan
  constexpr int SPB  = 16/NSH;        // states per thread
  constexpr int CH   = DI*16;         // channels per chunk in agg/carry
  constexpr int NCB  = CH/64;         // carry blocks (each owns 64 channels)
  constexpr int NZ   = DI/4;          // z values held per thread
  constexpr int R0SZ = DI*64;         // region0: SX (DIM*64) / xs+halo (DI*64) / dt (DI*49)
  constexpr int O_SXC = R0SZ;         // DI*49
  constexpr int O_SB  = O_SXC + DI*49;// 16*49
  constexpr int O_SC  = O_SB + 16*49; // 16*49
  constexpr int O_SY  = O_SC + 16*49; // DI*49  (also carry scratch 1024)
  constexpr int O_DTP = O_SY + DI*49; // DTR*48
  constexpr int SMEM  = O_DTP + DTR*48 + 16;
  __shared__ float sm[SMEM];

  const int tid   = threadIdx.x;
  const int chunk = blockIdx.x;
  const int t0    = chunk*TCH;

  // ---- P0: load x (+optional BN-normalize) into region0; cols 0..50 = t0-3..t0+47
  for (int idx = tid; idx < DIM*64; idx += 256){
    int c = idx >> 6, i2 = idx & 63;
    int t = t0 - 3 + i2;
    float v = 0.f;
    if (i2 < 51 && t >= 0){
      if constexpr (DOBN){
        float raw = a.x0[c*L_TOT + t];
        float bm = a.bstats[2*c]*(1.f/L_TOT);
        float bv = a.bstats[2*c+1]*(1.f/L_TOT) - bm*bm;
        v = (raw - bm)*rsqrtf(bv+BN_EPS)*a.bg[c] + a.bbp[c];
      } else {
        v = (c < 16) ? a.x0[c*L_TOT + t] : a.x1[(c-16)*L_TOT + t];
      }
    }
    sm[idx] = v;
  }
  __syncthreads();

  // ---- P1: LayerNorm per column, in place
  if (tid < 64){
    float s = 0.f, s2 = 0.f;
#pragma unroll
    for (int c = 0; c < DIM; c++){
      float v = sm[c*64 + tid];
      s += v; s2 += v*v;
    }
    float m  = s*(1.f/DIM);
    float var = s2*(1.f/DIM) - m*m;
    float rs = rsqrtf(var + BN_EPS);
#pragma unroll
    for (int c = 0; c < DIM; c++){
      float v = sm[c*64 + tid];
      sm[c*64 + tid] = (v-m)*rs*a.lnw[c] + a.lnb[c];
    }
  }
  __syncthreads();

  // ---- P2: in-proj.  xs rows -> region0 (over SX), z rows -> registers
  const int i   = tid & 63;
  const int r0w = tid >> 6;
  float zreg[NZ];
  {
    float xn[DIM];
#pragma unroll
    for (int c = 0; c < DIM; c++) xn[c] = sm[c*64 + i];
    __syncthreads();                     // everyone finished reading SX
    int zi = 0;
    for (int r = r0w; r < 2*DI; r += 4){
      float acc = 0.f;
#pragma unroll
      for (int c = 0; c < DIM; c++) acc += xn[c]*a.inw[r*DIM + c];
      if (r < DI){
        if (i < 51) sm[r*64 + i] = (t0 == 0 && i < 3) ? 0.f : acc;
      } else {
        zreg[zi++] = acc;                // z for (row r-DI, col i) kept in regs
      }
    }
  }
  __syncthreads();

  // ---- P3: causal depthwise conv (kw=4) + SiLU -> SXC
  for (int idx = tid; idx < DI*48; idx += 256){
    int d = idx / 48, j = idx - d*48;
    const float* xr = &sm[d*64 + j];     // xr[k] = xs[t-3+k]
    float acc = a.cb[d] + a.cw[d*4+0]*xr[0] + a.cw[d*4+1]*xr[1]
                        + a.cw[d*4+2]*xr[2] + a.cw[d*4+3]*xr[3];
    sm[O_SXC + d*49 + j] = acc * fsigmoid(acc);
  }
  __syncthreads();

  // ---- P4: x-proj -> dtp | B | C
  {
    constexpr int NR = (ROWS + 3) / 4;
    float acc[NR];
#pragma unroll
    for (int rr = 0; rr < NR; rr++) acc[rr] = 0.f;
    for (int db = 0; db < DI; db += 16){
      float xcol[16];
#pragma unroll
      for (int k = 0; k < 16; k++) xcol[k] = sm[O_SXC + (db+k)*49 + i];
#pragma unroll
      for (int rr = 0; rr < NR; rr++){
        int r = r0w + rr*4;
        if (r < ROWS){
          float a2 = 0.f;
#pragma unroll
          for (int k = 0; k < 16; k++) a2 += xcol[k]*a.xpw[r*DI + db + k];
          acc[rr] += a2;
        }
      }
    }
    if (i < 48){
#pragma unroll
      for (int rr = 0; rr < NR; rr++){
        int r = r0w + rr*4;
        if (r < ROWS){
          if (r < DTR)          sm[O_DTP + r*48 + i] = acc[rr];
          else if (r < DTR+16)  sm[O_SB + (r-DTR)*49 + i] = acc[rr];
          else                  sm[O_SC + (r-DTR-16)*49 + i] = acc[rr];
        }
      }
    }
  }
  __syncthreads();

  // ---- P5: dt = softplus(dtb + dtw*dtp) -> region0 (xs dead)
  for (int idx = tid; idx < DI*48; idx += 256){
    int d = idx / 48, j = idx - d*48;
    float pre = a.dtb[d] + a.dtw[d*DTR]*sm[O_DTP + j];
    if (DTR > 1) pre += a.dtw[d*DTR + DTR-1]*sm[O_DTP + (DTR-1)*48 + j];
    sm[d*49 + j] = fsoftplus(pre);
  }
  __syncthreads();

  // ---- P6: pass1 scan -> per-chunk (A,B) aggregates in global
  const int dd = tid / NSH;
  const int sh = tid - dd*NSH;
  float Av[SPB];
#pragma unroll
  for (int j = 0; j < SPB; j++) Av[j] = -__expf(a.Alog[dd*16 + sh*SPB + j]);
  {
    float Ar[SPB], Br[SPB];
#pragma unroll
    for (int j = 0; j < SPB; j++){ Ar[j] = 1.f; Br[j] = 0.f; }
    for (int t = 0; t < TCH; t++){
      float dtv = sm[dd*49 + t];
      float bb2 = dtv * sm[O_SXC + dd*49 + t];
#pragma unroll
      for (int j = 0; j < SPB; j++){
        float a2 = __expf(dtv*Av[j]);
        Ar[j] *= a2;
        Br[j] = a2*Br[j] + bb2*sm[O_SB + (sh*SPB+j)*49 + t];
      }
    }
    const int o = chunk*CH + tid*SPB;
    if constexpr (SPB == 4){
      *reinterpret_cast<float4*>(&a.aggA[o]) = make_float4(Ar[0],Ar[1],Ar[2],Ar[3]);
      *reinterpret_cast<float4*>(&a.aggB[o]) = make_float4(Br[0],Br[1],Br[2],Br[3]);
    } else {
      *reinterpret_cast<float2*>(&a.aggA[o]) = make_float2(Ar[0],Ar[1]);
      *reinterpret_cast<float2*>(&a.aggB[o]) = make_float2(Br[0],Br[1]);
    }
  }
  bar_signal(a.bar0);                       // release: WB publishes aggA/aggB

  // ---- carry scan (first NCB blocks): coherent float2 loads, 8-seg LDS prefix ----
  if (blockIdx.x < NCB){
    bar_wait(a.bar0, NCHUNK);
    constexpr int CH2 = CH/2;
    constexpr int SEG = NCHUNK/8;           // 96 chunks per segment
    const int chp = tid & 31;               // ch-pair slot (32 pairs = 64 ch/block)
    const int seg = tid >> 5;               // 8 segments
    const int c0  = seg*SEG;
    const int chb = blockIdx.x*32 + chp;    // float2 index within a chunk row
    const int chf = blockIdx.x*64 + chp*2;  // float index within a chunk row
    float2 aa = make_float2(1.f,1.f), bb3 = make_float2(0.f,0.f);
    for (int cb = c0; cb < c0+SEG; cb += 8){
      float2 av[8], bv[8];
#pragma unroll
      for (int k=0;k<8;k++){
        av[k] = ld_f2_coh(&a.aggA[2*((cb+k)*CH2 + chb)]);
        bv[k] = ld_f2_coh(&a.aggB[2*((cb+k)*CH2 + chb)]);
      }
#pragma unroll
      for (int k=0;k<8;k++){
        aa.x *= av[k].x;  bb3.x = av[k].x*bb3.x + bv[k].x;
        aa.y *= av[k].y;  bb3.y = av[k].y*bb3.y + bv[k].y;
      }
    }
    float* sA = &sm[O_SY];                  // [8][64] seg aggregates
    float* sB = &sm[O_SY + 512];
    sA[seg*64 + chp*2]   = aa.x;  sA[seg*64 + chp*2+1] = aa.y;
    sB[seg*64 + chp*2]   = bb3.x; sB[seg*64 + chp*2+1] = bb3.y;
    __syncthreads();
    if (tid < 64){
      float pa=1.f, pb=0.f;
      for (int g=0; g<8; g++){
        float ca = sA[g*64+tid], cb2 = sB[g*64+tid];
        sA[g*64+tid] = pa; sB[g*64+tid] = pb;
        float na = pa*ca, nb = ca*pb + cb2;
        pa = na; pb = nb;
      }
    }
    __syncthreads();
    float2 h = make_float2(sB[seg*64 + chp*2], sB[seg*64 + chp*2+1]);
    for (int cb = c0; cb < c0+SEG; cb += 8){
      float2 av[8], bv[8];
#pragma unroll
      for (int k=0;k<8;k++){
        av[k] = ld_f2_coh(&a.aggA[2*((cb+k)*CH2 + chb)]);
        bv[k] = ld_f2_coh(&a.aggB[2*((cb+k)*CH2 + chb)]);
      }
#pragma unroll
      for (int k=0;k<8;k++){
        *reinterpret_cast<float2*>(&a.carry[(cb+k)*CH + chf]) = h;
        h.x = av[k].x*h.x + bv[k].x;
        h.y = av[k].y*h.y + bv[k].y;
      }
    }
    bar_signal(a.bar1);                     // release: WB publishes carry[]
  }
  bar_wait(a.bar1, NCB);                    // relaxed poll only - NO invalidate

  // ---- pass2: h update + y = sum_s h*C + xc*D -> SY  (xc/dt/B/C still in LDS!)
  {
    float h[SPB];
    const int o = chunk*CH + tid*SPB;
    {
      float2 h01 = ld_f2_coh(&a.carry[o]);  // coherent read of cross-block data
      h[0]=h01.x; h[1]=h01.y;
      if constexpr (SPB == 4){
        float2 h23 = ld_f2_coh(&a.carry[o+2]);
        h[2]=h23.x; h[3]=h23.y;
      }
    }
    const float Dv = a.Dp[dd];
    for (int t = 0; t < TCH; t++){
      float dtv = sm[dd*49 + t];
      float xcv = sm[O_SXC + dd*49 + t];
      float bb2 = dtv*xcv;
      float p = 0.f;
#pragma unroll
      for (int j = 0; j < SPB; j++){
        float a2 = __expf(dtv*Av[j]);
        h[j] = a2*h[j] + bb2*sm[O_SB + (sh*SPB+j)*49 + t];
        p += h[j]*sm[O_SC + (sh*SPB+j)*49 + t];
      }
#pragma unroll
      for (int o2 = 1; o2 < NSH; o2 <<= 1) p += __shfl_xor(p, o2);
      if (sh == 0) sm[O_SY + dd*49 + t] = p + xcv*Dv;
    }
  }
  __syncthreads();

  // ---- gate: y *= silu(z), z from registers (thread holds rows r0w+4u, col i)
  if (i >= 3 && i < 51){
#pragma unroll
    for (int u = 0; u < NZ; u++){
      float zv = zreg[u];
      sm[O_SY + (r0w + 4*u)*49 + (i-3)] *= zv*fsigmoid(zv);
    }
  }
  __syncthreads();

  // ---- out-proj + residual -> padded bf16 conv input
  {
    constexpr int NO = DIM/4;
    float acc[NO];
#pragma unroll
    for (int rr = 0; rr < NO; rr++) acc[rr] = 0.f;
    for (int db = 0; db < DI; db += 16){
      float ycol[16];
#pragma unroll
      for (int k = 0; k < 16; k++) ycol[k] = sm[O_SY + (db+k)*49 + i];
#pragma unroll
      for (int rr = 0; rr < NO; rr++){
        int r = r0w + rr*4;
        float a2 = 0.f;
#pragma unroll
        for (int k = 0; k < 16; k++) a2 += ycol[k]*a.ow[r*DI + db + k];
        acc[rr] += a2;
      }
    }
    if (i < 48){
      const int t  = t0 + i;
      const int zz = chunk / 48, yy = chunk - zz*48;
      const int pb2 = (zz+1)*2500 + (yy+1)*50 + (i+1);
#pragma unroll
      for (int rr = 0; rr < NO; rr++){
        int r = r0w + rr*4;
        float res;
        if (RES == 0){
          res = (r < 16) ? a.r0src[r*L_TOT + t] : a.r1src[(r-16)*L_TOT + t];
        } else {
          float bm = a.bstats[2*r]*(1.f/L_TOT);
          float bv = a.bstats[2*r+1]*(1.f/L_TOT) - bm*bm;
          res = (a.r0src[r*L_TOT + t] - bm)*rsqrtf(bv+BN_EPS)*a.bg[r] + a.bbp[r];
        }
        a.rp[r*PCH + pb2] = f2bf(acc[rr] + res);
      }
    }
  }
}

// ---------------- conv3d via MFMA implicit GEMM + fused BN partial sums -----------
template<int IC>
__global__ __launch_bounds__(256) void k_conv_mfma(const unsigned short* __restrict__ bin,
                         const unsigned short* __restrict__ wA,
                         const float* __restrict__ bias, float* __restrict__ out,
                         float* __restrict__ stats) {
  constexpr int NKB = (IC==32) ? 27 : 14;
  __shared__ float sred[32];
  if (threadIdx.x < 32) sred[threadIdx.x] = 0.f;
  __syncthreads();
  const int lane = threadIdx.x & 63;
  const int n = lane & 15, quad = lane >> 4;
  const int tile = blockIdx.x*4 + (threadIdx.x >> 6);
  const int t = tile*16 + n;
  int zz = t / 2304;
  int r2 = t - zz*2304;
  int yy = r2 / 48;
  int xx = r2 - yy*48;
  int pb = (zz+1)*2500 + (yy+1)*50 + (xx+1);
  const unsigned short* bp[8];
#pragma unroll
  for (int j=0;j<8;j++){
    int e = quad*8 + j;
    int ic = (IC==32) ? e : (e & 15);
    bp[j] = bin + ic*PCH + pb;
  }
  const int rq = (IC==32) ? 0 : (quad >> 1);
  f32x4 acc = {0.f, 0.f, 0.f, 0.f};
#pragma unroll
  for (int kb=0; kb<NKB; kb++){
    bf16x8 af = *reinterpret_cast<const bf16x8*>(wA + (size_t)((kb*4+quad)*16 + n)*8);
    int off;
    if (IC==32) off = off3c(kb);
    else        off = rq ? off3c(2*kb+1) : off3c(2*kb);
    bf16x8 bf;
#pragma unroll
    for (int j=0;j<8;j++) bf[j] = (short)bp[j][off];
    acc = __builtin_amdgcn_mfma_f32_16x16x32_bf16(af, bf, acc, 0, 0, 0);
  }
  float vs[4];
#pragma unroll
  for (int reg=0; reg<4; reg++){
    int m = quad*4 + reg;
    float v = acc[reg] + bias[m];
    out[m*L_TOT + t] = v;
    vs[reg] = v;
  }
#pragma unroll
  for (int reg=0; reg<4; reg++){
    float a = vs[reg], b2 = vs[reg]*vs[reg];
#pragma unroll
    for (int o=1; o<16; o<<=1){ a += __shfl_xor(a,o); b2 += __shfl_xor(b2,o); }
    if (n == 0){
      atomicAdd(&sred[quad*4+reg], a);
      atomicAdd(&sred[16 + quad*4+reg], b2);
    }
  }
  __syncthreads();
  if (threadIdx.x < 16){
    atomicAdd(&stats[2*threadIdx.x],   sred[threadIdx.x]);
    atomicAdd(&stats[2*threadIdx.x+1], sred[16+threadIdx.x]);
  }
}

// ---------------- BN normalize, float4 --------------------------------------------
__global__ void k_bn_norm4(const float* __restrict__ raw, const float* __restrict__ stats,
                           const float* __restrict__ g, const float* __restrict__ b,
                           float* __restrict__ out) {
  int i = blockIdx.x*256 + threadIdx.x;         // over 16*L_TOT/4
  int c = i / (L_TOT/4);
  int tq = i - c*(L_TOT/4);
  float m = stats[2*c]*(1.f/L_TOT);
  float v = stats[2*c+1]*(1.f/L_TOT) - m*m;
  float sc = rsqrtf(v+BN_EPS)*g[c];
  float bs = b[c] - m*sc;
  float4 x = *reinterpret_cast<const float4*>(raw + c*L_TOT + tq*4);
  float4 o = make_float4(x.x*sc+bs, x.y*sc+bs, x.z*sc+bs, x.w*sc+bs);
  *reinterpret_cast<float4*>(out + c*L_TOT + tq*4) = o;
}

// =================================================================================
extern "C" void kernel_launch(void* const* d_in, const int* in_sizes, int n_in,
                              void* d_out, int out_size, void* d_ws, size_t ws_size,
                              hipStream_t stream) {
  const float* l        = (const float*)d_in[0];
  const float* s        = (const float*)d_in[1];
  const float* m1_ln_w  = (const float*)d_in[2];
  const float* m1_ln_b  = (const float*)d_in[3];
  const float* m1_in_w  = (const float*)d_in[4];
  const float* m1_cw    = (const float*)d_in[5];
  const float* m1_cb    = (const float*)d_in[6];
  const float* m1_xp_w  = (const float*)d_in[7];
  const float* m1_dt_w  = (const float*)d_in[8];
  const float* m1_dt_b  = (const float*)d_in[9];
  const float* m1_Alog  = (const float*)d_in[10];
  const float* m1_D     = (const float*)d_in[11];
  const float* m1_out_w = (const float*)d_in[12];
  const float* m2_ln_w  = (const float*)d_in[13];
  const float* m2_ln_b  = (const float*)d_in[14];
  const float* m2_in_w  = (const float*)d_in[15];
  const float* m2_cw    = (const float*)d_in[16];
  const float* m2_cb    = (const float*)d_in[17];
  const float* m2_xp_w  = (const float*)d_in[18];
  const float* m2_dt_w  = (const float*)d_in[19];
  const float* m2_dt_b  = (const float*)d_in[20];
  const float* m2_Alog  = (const float*)d_in[21];
  const float* m2_D     = (const float*)d_in[22];
  const float* m2_out_w = (const float*)d_in[23];
  const float* c1_w     = (const float*)d_in[24];
  const float* c1_b     = (const float*)d_in[25];
  const float* bn1_g    = (const float*)d_in[26];
  const float* bn1_b    = (const float*)d_in[27];
  const float* c2_w     = (const float*)d_in[28];
  const float* c2_b     = (const float*)d_in[29];
  const float* bn2_g    = (const float*)d_in[30];
  const float* bn2_b    = (const float*)d_in[31];

  float* ws = (float*)d_ws;
  const size_t L = L_TOT;
  float* conv1raw = ws;                  // 16L
  float* conv2raw = ws + 16*L;           // 16L
  float* aggA     = ws + 32*L;           // 786432
  float* aggB     = aggA + 786432;
  float* carry    = aggB + 786432;
  float* stats1   = carry + 786432;      // 32
  float* stats2   = stats1 + 32;         // 32
  unsigned* bar   = (unsigned*)(stats2 + 32);             // 4 barrier counters
  unsigned short* bfin = (unsigned short*)(stats2 + 48);  // 32ch * PCH bf16
  unsigned short* wA1  = bfin + 32*PCH;  // 13824 ushorts
  unsigned short* wA2  = wA1 + 13824;    // 7168 ushorts

  // setup: weight pack + zero bfin halo buffer + zero stats + zero barrier counters
  k_setup<<<2813,256,0,stream>>>(c1_w, wA1, c2_w, wA2, stats1, bar, (float*)bfin);

  // ================= stage 1: mamba(dim=32, di=64) persistent + conv1 ============
  MambaArgs a1 = { l, s, stats1, bn1_g, bn1_b,
                   m1_ln_w, m1_ln_b, m1_in_w, m1_cw, m1_cb, m1_xp_w,
                   m1_dt_w, m1_dt_b, m1_Alog, m1_D, m1_out_w,
                   l, s, aggA, aggB, carry, bar+0, bar+1, bfin };
  k_mamba<32,64,2,false,0><<<768,256,0,stream>>>(a1);
  k_conv_mfma<32><<<576,256,0,stream>>>(bfin, wA1, c1_b, conv1raw, stats1);

  // ================= stage 2: mamba(dim=16, di=32) persistent + conv2 ============
  MambaArgs a2 = { conv1raw, conv1raw, stats1, bn1_g, bn1_b,
                   m2_ln_w, m2_ln_b, m2_in_w, m2_cw, m2_cb, m2_xp_w,
                   m2_dt_w, m2_dt_b, m2_Alog, m2_D, m2_out_w,
                   conv1raw, conv1raw, aggA, aggB, carry, bar+2, bar+3, bfin };
  k_mamba<16,32,1,true,1><<<768,256,0,stream>>>(a2);
  k_conv_mfma<16><<<576,256,0,stream>>>(bfin, wA2, c2_b, conv2raw, stats2);
  k_bn_norm4<<<576,256,0,stream>>>(conv2raw, stats2, bn2_g, bn2_b, (float*)d_out);
}

// Round 6
// 314.346 us; speedup vs baseline: 1.9404x; 1.9404x over previous
//
#include <hip/hip_runtime.h>
#include <math.h>

#define L_TOT 36864
#define BN_EPS 1e-5f
#define PCH 45000   // padded channel stride: 18*50*50

typedef __attribute__((ext_vector_type(8))) short bf16x8;
typedef __attribute__((ext_vector_type(4))) float f32x4;

__device__ __forceinline__ float fsigmoid(float x){ return 1.f/(1.f+__expf(-x)); }
__device__ __forceinline__ float fsoftplus(float x){
  float e = __expf(x);
  return (x>20.f)? x : __logf(1.f+e);
}
__device__ __forceinline__ unsigned short f2bf(float x){
  union { float f; unsigned u; } cv; cv.f = x;
  unsigned r = (cv.u + 0x7FFFu + ((cv.u>>16)&1u)) >> 16;
  return (unsigned short)r;
}
__host__ __device__ constexpr int off3c(int r){
  return (r>=27) ? 0 : ((r/9)-1)*2500 + (((r%9)/3)-1)*50 + ((r%3)-1);
}

// ---------------- setup: pack conv weights + zero bf16 halo buffer + zero stats ---
__global__ void k_setup(const float* __restrict__ w1, unsigned short* __restrict__ wA1,
                        const float* __restrict__ w2, unsigned short* __restrict__ wA2,
                        float* __restrict__ stats, float* __restrict__ bfz) {
  int b = blockIdx.x, tid = threadIdx.x;
  int idx = b*256 + tid;
  if (idx < 16*PCH) bfz[idx] = 0.f;     // zero all 32 bf16 channels (as 32-bit words)
  if (b < 4){
    int k = b*256 + tid;
    if (k < 864){
      int ic = k & 31, r = k >> 5;
      for (int m=0;m<16;m++){
        float v = (r < 27) ? w1[m*32*27 + ic*27 + r] : 0.f;
        wA1[(((k>>3)*16) + m)*8 + (k&7)] = f2bf(v);
      }
    }
  } else if (b < 6){
    int k = (b-4)*256 + tid;
    if (k < 448){
      int ic = k & 15, r = k >> 4;
      for (int m=0;m<16;m++){
        float v = (r < 27) ? w2[m*16*27 + ic*27 + r] : 0.f;
        wA2[(((k>>3)*16) + m)*8 + (k&7)] = f2bf(v);
      }
    }
  } else if (b == 6){
    if (tid < 64) stats[tid] = 0.f;
  }
}

// =================================================================================
// k_front: fused LN (+BN-on-read) + in-proj + causal dwconv/SiLU + x-proj + dt +
//          pass1 chunk aggregates.  One block = one chunk of 48 timesteps.
// Region0 (DI*64 floats) is time-aliased: SX -> xs(+halo) -> dt.
// In-proj uses 4-wide unroll-and-jam (4 independent FMA chains hide dep latency).
// =================================================================================
template<int DIM, int DI, int DTR, bool DOBN>
__global__ __launch_bounds__(256) void k_front(
    const float* __restrict__ x0, const float* __restrict__ x1,
    const float* __restrict__ bstats, const float* __restrict__ bg, const float* __restrict__ bbp,
    const float* __restrict__ lnw, const float* __restrict__ lnb,
    const float* __restrict__ inw,
    const float* __restrict__ cw, const float* __restrict__ cb,
    const float* __restrict__ xpw,
    const float* __restrict__ dtw, const float* __restrict__ dtb,
    const float* __restrict__ Alog,
    float* __restrict__ xcg, float* __restrict__ zg,
    float* __restrict__ dtpg, float* __restrict__ Bg, float* __restrict__ Cg,
    float* __restrict__ aggA, float* __restrict__ aggB)
{
  constexpr int TCH  = 48;
  constexpr int ROWS = DTR + 32;
  constexpr int NSH  = 256/DI;        // threads per d-channel in scan
  constexpr int SPB  = 16/NSH;        // states per thread
  constexpr int CH   = DI*16;
  constexpr int R0SZ = DI*64;         // region0: SX (DIM*64) / xs+halo (DI*64) / dt (DI*49)
  constexpr int O_SXC = R0SZ;         // DI*49
  constexpr int O_SB  = O_SXC + DI*49;// 16*49
  constexpr int O_SC  = O_SB + 16*49; // 16*49
  constexpr int O_DTP = O_SC + 16*49; // DTR*48
  constexpr int SMEM  = O_DTP + DTR*48 + 64;
  __shared__ float sm[SMEM];

  const int tid   = threadIdx.x;
  const int chunk = blockIdx.x;
  const int t0    = chunk*TCH;

  // ---- P0: load x (+optional BN-normalize) into region0; cols 0..50 = t0-3..t0+47
  for (int idx = tid; idx < DIM*64; idx += 256){
    int c = idx >> 6, i2 = idx & 63;
    int t = t0 - 3 + i2;
    float v = 0.f;
    if (i2 < 51 && t >= 0){
      if constexpr (DOBN){
        float raw = x0[c*L_TOT + t];
        float bm = bstats[2*c]*(1.f/L_TOT);
        float bv = bstats[2*c+1]*(1.f/L_TOT) - bm*bm;
        v = (raw - bm)*rsqrtf(bv+BN_EPS)*bg[c] + bbp[c];
      } else {
        v = (c < 16) ? x0[c*L_TOT + t] : x1[(c-16)*L_TOT + t];
      }
    }
    sm[idx] = v;
  }
  __syncthreads();

  // ---- P1: LayerNorm per column, in place (cols >=51 all-zero, stay finite)
  if (tid < 64){
    float s = 0.f, s2 = 0.f;
#pragma unroll
    for (int c = 0; c < DIM; c++){
      float v = sm[c*64 + tid];
      s += v; s2 += v*v;
    }
    float m  = s*(1.f/DIM);
    float var = s2*(1.f/DIM) - m*m;
    float rs = rsqrtf(var + BN_EPS);
#pragma unroll
    for (int c = 0; c < DIM; c++){
      float v = sm[c*64 + tid];
      sm[c*64 + tid] = (v-m)*rs*lnw[c] + lnb[c];
    }
  }
  __syncthreads();

  // ---- P2: in-proj, 4-wide jam.  xs rows -> region0 (over SX), z rows -> global
  const int i   = tid & 63;
  const int r0w = __builtin_amdgcn_readfirstlane(tid >> 6);
  {
    constexpr int KTOT = 2*DI/4;       // rows per thread (32 or 16)
    float xn[DIM];
#pragma unroll
    for (int c = 0; c < DIM; c++) xn[c] = sm[c*64 + i];
    __syncthreads();                   // everyone finished reading SX; region0 reusable
#pragma unroll
    for (int kg = 0; kg < KTOT; kg += 4){
      float acc[4] = {0.f, 0.f, 0.f, 0.f};
#pragma unroll
      for (int c = 0; c < DIM; c++){
        float xv = xn[c];
#pragma unroll
        for (int u = 0; u < 4; u++)
          acc[u] += xv * inw[(r0w + 4*(kg+u))*DIM + c];
      }
      if (kg < KTOT/2){                // xs rows (r < DI)
        if (i < 51){
#pragma unroll
          for (int u = 0; u < 4; u++){
            int r = r0w + 4*(kg+u);
            sm[r*64 + i] = (t0 == 0 && i < 3) ? 0.f : acc[u];
          }
        }
      } else {                         // z rows -> global
        if (i >= 3 && i < 51){
#pragma unroll
          for (int u = 0; u < 4; u++){
            int r = r0w + 4*(kg+u) - DI;
            zg[r*L_TOT + t0 + i - 3] = acc[u];
          }
        }
      }
    }
  }
  __syncthreads();

  // ---- P3: causal depthwise conv (kw=4) + SiLU -> SXC
  for (int idx = tid; idx < DI*48; idx += 256){
    int d = idx / 48, j = idx - d*48;
    const float* xr = &sm[d*64 + j];     // xr[k] = xs[t-3+k]
    float acc = cb[d] + cw[d*4+0]*xr[0] + cw[d*4+1]*xr[1]
                      + cw[d*4+2]*xr[2] + cw[d*4+3]*xr[3];
    sm[O_SXC + d*49 + j] = acc * fsigmoid(acc);
  }
  __syncthreads();

  // ---- P4: x-proj -> dtp | B | C
  {
    constexpr int NR = (ROWS + 3) / 4;
    float acc[NR];
#pragma unroll
    for (int rr = 0; rr < NR; rr++) acc[rr] = 0.f;
    for (int db = 0; db < DI; db += 16){
      float xcol[16];
#pragma unroll
      for (int k = 0; k < 16; k++) xcol[k] = sm[O_SXC + (db+k)*49 + i];
#pragma unroll
      for (int rr = 0; rr < NR; rr++){
        int r = r0w + rr*4;
        if (r < ROWS){
          float a2 = 0.f;
#pragma unroll
          for (int k = 0; k < 16; k++) a2 += xcol[k]*xpw[r*DI + db + k];
          acc[rr] += a2;
        }
      }
    }
    if (i < 48){
#pragma unroll
      for (int rr = 0; rr < NR; rr++){
        int r = r0w + rr*4;
        if (r < ROWS){
          if (r < DTR)          sm[O_DTP + r*48 + i] = acc[rr];
          else if (r < DTR+16)  sm[O_SB + (r-DTR)*49 + i] = acc[rr];
          else                  sm[O_SC + (r-DTR-16)*49 + i] = acc[rr];
        }
      }
    }
  }
  __syncthreads();

  // ---- P5: dt = softplus(dtb + dtw*dtp) -> region0 (xs dead)
  for (int idx = tid; idx < DI*48; idx += 256){
    int d = idx / 48, j = idx - d*48;
    float pre = dtb[d] + dtw[d*DTR]*sm[O_DTP + j];
    if (DTR > 1) pre += dtw[d*DTR + DTR-1]*sm[O_DTP + (DTR-1)*48 + j];
    sm[d*49 + j] = fsoftplus(pre);
  }
  __syncthreads();

  // ---- P6: spill xc/dtp/B/C to global (stores fly during pass1 compute)
  for (int idx = tid; idx < DI*12; idx += 256){
    int d = idx / 12, q = idx - d*12;
    float4 v = make_float4(sm[O_SXC + d*49 + q*4+0], sm[O_SXC + d*49 + q*4+1],
                           sm[O_SXC + d*49 + q*4+2], sm[O_SXC + d*49 + q*4+3]);
    *reinterpret_cast<float4*>(xcg + d*L_TOT + t0 + q*4) = v;
  }
  for (int idx = tid; idx < ROWS*48; idx += 256){
    int r = idx / 48, j = idx - r*48;
    if (r < DTR)         dtpg[r*L_TOT + t0 + j]        = sm[O_DTP + r*48 + j];
    else if (r < DTR+16) Bg[(r-DTR)*L_TOT + t0 + j]    = sm[O_SB + (r-DTR)*49 + j];
    else                 Cg[(r-DTR-16)*L_TOT + t0 + j] = sm[O_SC + (r-DTR-16)*49 + j];
  }

  // ---- P7: pass1 scan -> per-chunk (A,B) aggregates
  {
    const int d  = tid / NSH;
    const int sh = tid - d*NSH;
    float Av[SPB], Ar[SPB], Br[SPB];
#pragma unroll
    for (int j = 0; j < SPB; j++){
      Av[j] = -__expf(Alog[d*16 + sh*SPB + j]);
      Ar[j] = 1.f; Br[j] = 0.f;
    }
    for (int t = 0; t < TCH; t++){
      float dtv = sm[d*49 + t];
      float bb2 = dtv * sm[O_SXC + d*49 + t];
#pragma unroll
      for (int j = 0; j < SPB; j++){
        float a2 = __expf(dtv*Av[j]);
        Ar[j] *= a2;
        Br[j] = a2*Br[j] + bb2*sm[O_SB + (sh*SPB+j)*49 + t];
      }
    }
    const int o = chunk*CH + tid*SPB;
    if constexpr (SPB == 4){
      *reinterpret_cast<float4*>(&aggA[o]) = make_float4(Ar[0],Ar[1],Ar[2],Ar[3]);
      *reinterpret_cast<float4*>(&aggB[o]) = make_float4(Br[0],Br[1],Br[2],Br[3]);
    } else {
      *reinterpret_cast<float2*>(&aggA[o]) = make_float2(Ar[0],Ar[1]);
      *reinterpret_cast<float2*>(&aggB[o]) = make_float2(Br[0],Br[1]);
    }
  }
}

// ---------------- parallel scan over chunk aggregates -> carries ------------------
template<int NCH>
__global__ __launch_bounds__(1024) void k_carry(const float* __restrict__ aggA,
                        const float* __restrict__ aggB,
                        float* __restrict__ carry, int CH) {
  constexpr int SEG = NCH/16;
  int lane = threadIdx.x & 63;
  int seg  = threadIdx.x >> 6;
  int ch   = blockIdx.x*64 + lane;
  int c0   = seg*SEG;
  float a = 1.f, b = 0.f;
  for (int cb=c0; cb<c0+SEG; cb+=8){
    float av[8], bv[8];
#pragma unroll
    for (int k=0;k<8;k++){ av[k]=aggA[(cb+k)*CH+ch]; bv[k]=aggB[(cb+k)*CH+ch]; }
#pragma unroll
    for (int k=0;k<8;k++){ a = a*av[k]; b = av[k]*b + bv[k]; }
  }
  __shared__ float sa[16][64], sb[16][64];
  sa[seg][lane]=a; sb[seg][lane]=b;
  __syncthreads();
  if (seg==0){
    float pa=1.f, pb=0.f;
    for (int g=0; g<16; g++){
      float ca=sa[g][lane], cb2=sb[g][lane];
      sa[g][lane]=pa; sb[g][lane]=pb;
      float na = pa*ca;
      float nb = ca*pb + cb2;
      pa=na; pb=nb;
    }
  }
  __syncthreads();
  float h = sb[seg][lane];
  for (int cb=c0; cb<c0+SEG; cb+=8){
    float av[8], bv[8];
#pragma unroll
    for (int k=0;k<8;k++){ av[k]=aggA[(cb+k)*CH+ch]; bv[k]=aggB[(cb+k)*CH+ch]; }
#pragma unroll
    for (int k=0;k<8;k++){ carry[(cb+k)*CH+ch]=h; h = av[k]*h + bv[k]; }
  }
}

// =================================================================================
// k_back: fused pass2 scan + z-gate + out-proj + residual -> bf16 padded layout.
// =================================================================================
template<int DIM, int DI, int DTR, int RES>
__global__ __launch_bounds__(256) void k_back(
    const float* __restrict__ xcg, const float* __restrict__ zg,
    const float* __restrict__ dtpg, const float* __restrict__ Bg, const float* __restrict__ Cg,
    const float* __restrict__ dtw, const float* __restrict__ dtb,
    const float* __restrict__ Alog, const float* __restrict__ Dp,
    const float* __restrict__ carry,
    const float* __restrict__ ow,
    const float* __restrict__ r0src, const float* __restrict__ r1src,
    const float* __restrict__ bstats, const float* __restrict__ bg, const float* __restrict__ bbp,
    unsigned short* __restrict__ rp)
{
  constexpr int TCH = 48;
  constexpr int NSH = 256/DI;
  constexpr int SPB = 16/NSH;
  constexpr int O_SXC = 0;               // DI*49
  constexpr int O_SDT = O_SXC + DI*49;   // DI*49
  constexpr int O_SB  = O_SDT + DI*49;   // 16*49
  constexpr int O_SC  = O_SB + 16*49;    // 16*49
  constexpr int O_SY  = O_SC + 16*49;    // DI*49
  constexpr int O_DTP = O_SY + DI*49;    // DTR*48
  constexpr int SMEM  = O_DTP + DTR*48 + 64;
  __shared__ float sm[SMEM];
  const int tid   = threadIdx.x;
  const int chunk = blockIdx.x;
  const int t0    = chunk*TCH;

  // ---- load xc / B / C / dtp
  for (int idx = tid; idx < DI*12; idx += 256){
    int d = idx / 12, q = idx - d*12;
    float4 v = *reinterpret_cast<const float4*>(xcg + d*L_TOT + t0 + q*4);
    sm[O_SXC + d*49 + q*4+0] = v.x; sm[O_SXC + d*49 + q*4+1] = v.y;
    sm[O_SXC + d*49 + q*4+2] = v.z; sm[O_SXC + d*49 + q*4+3] = v.w;
  }
  for (int idx = tid; idx < (DTR+32)*48; idx += 256){
    int r = idx / 48, j = idx - r*48;
    if (r < DTR)         sm[O_DTP + r*48 + j]        = dtpg[r*L_TOT + t0 + j];
    else if (r < DTR+16) sm[O_SB + (r-DTR)*49 + j]   = Bg[(r-DTR)*L_TOT + t0 + j];
    else                 sm[O_SC + (r-DTR-16)*49 + j]= Cg[(r-DTR-16)*L_TOT + t0 + j];
  }
  __syncthreads();
  // ---- dt = softplus(dtb + dtw*dtp)
  for (int idx = tid; idx < DI*48; idx += 256){
    int d = idx / 48, j = idx - d*48;
    float pre = dtb[d] + dtw[d*DTR]*sm[O_DTP + j];
    if (DTR > 1) pre += dtw[d*DTR + DTR-1]*sm[O_DTP + 48 + j];
    sm[O_SDT + d*49 + j] = fsoftplus(pre);
  }
  __syncthreads();

  // ---- pass2 scan: h update + y = sum_s h*C + xc*D -> SY
  {
    const int d  = tid / NSH;
    const int sh = tid - d*NSH;
    float Av[SPB], h[SPB];
#pragma unroll
    for (int j = 0; j < SPB; j++){
      Av[j] = -__expf(Alog[d*16 + sh*SPB + j]);
      h[j]  = carry[chunk*(DI*16) + tid*SPB + j];
    }
    const float Dv = Dp[d];
    for (int t = 0; t < TCH; t++){
      float dtv = sm[O_SDT + d*49 + t];
      float xcv = sm[O_SXC + d*49 + t];
      float bb2 = dtv*xcv;
      float p = 0.f;
#pragma unroll
      for (int j = 0; j < SPB; j++){
        float a2 = __expf(dtv*Av[j]);
        h[j] = a2*h[j] + bb2*sm[O_SB + (sh*SPB+j)*49 + t];
        p += h[j]*sm[O_SC + (sh*SPB+j)*49 + t];
      }
#pragma unroll
      for (int o = 1; o < NSH; o <<= 1) p += __shfl_xor(p, o);
      if (sh == 0) sm[O_SY + d*49 + t] = p + xcv*Dv;
    }
  }
  __syncthreads();
  // ---- gate: y *= silu(z)   (z streamed from global, never staged)
  for (int idx = tid; idx < DI*12; idx += 256){
    int d = idx / 12, q = idx - d*12;
    float4 zv = *reinterpret_cast<const float4*>(zg + d*L_TOT + t0 + q*4);
    sm[O_SY + d*49 + q*4+0] *= zv.x*fsigmoid(zv.x);
    sm[O_SY + d*49 + q*4+1] *= zv.y*fsigmoid(zv.y);
    sm[O_SY + d*49 + q*4+2] *= zv.z*fsigmoid(zv.z);
    sm[O_SY + d*49 + q*4+3] *= zv.w*fsigmoid(zv.w);
  }
  __syncthreads();

  // ---- out-proj + residual -> padded bf16 conv input
  {
    const int col = tid & 63;
    const int r0w = __builtin_amdgcn_readfirstlane(tid >> 6);
    constexpr int NO = DIM/4;
    float acc[NO];
#pragma unroll
    for (int rr = 0; rr < NO; rr++) acc[rr] = 0.f;
    for (int db = 0; db < DI; db += 16){
      float ycol[16];
#pragma unroll
      for (int k = 0; k < 16; k++) ycol[k] = sm[O_SY + (db+k)*49 + col];
#pragma unroll
      for (int rr = 0; rr < NO; rr++){
        int r = r0w + rr*4;
        float a2 = 0.f;
#pragma unroll
        for (int k = 0; k < 16; k++) a2 += ycol[k]*ow[r*DI + db + k];
        acc[rr] += a2;
      }
    }
    if (col < 48){
      const int t  = t0 + col;
      const int zz = chunk / 48, yy = chunk - zz*48;     // 48 cols = one (zz,yy) row
      const int pb = (zz+1)*2500 + (yy+1)*50 + (col+1);
#pragma unroll
      for (int rr = 0; rr < NO; rr++){
        int r = r0w + rr*4;
        float res;
        if (RES == 0){
          res = (r < 16) ? r0src[r*L_TOT + t] : r1src[(r-16)*L_TOT + t];
        } else {
          float bm = bstats[2*r]*(1.f/L_TOT);
          float bv = bstats[2*r+1]*(1.f/L_TOT) - bm*bm;
          res = (r0src[r*L_TOT + t] - bm)*rsqrtf(bv+BN_EPS)*bg[r] + bbp[r];
        }
        rp[r*PCH + pb] = f2bf(acc[rr] + res);
      }
    }
  }
}

// ---------------- conv3d via MFMA implicit GEMM + fused BN partial sums -----------
template<int IC>
__global__ __launch_bounds__(256) void k_conv_mfma(const unsigned short* __restrict__ bin,
                         const unsigned short* __restrict__ wA,
                         const float* __restrict__ bias, float* __restrict__ out,
                         float* __restrict__ stats) {
  constexpr int NKB = (IC==32) ? 27 : 14;
  __shared__ float sred[32];
  if (threadIdx.x < 32) sred[threadIdx.x] = 0.f;
  __syncthreads();
  const int lane = threadIdx.x & 63;
  const int n = lane & 15, quad = lane >> 4;
  const int tile = blockIdx.x*4 + (threadIdx.x >> 6);
  const int t = tile*16 + n;
  int zz = t / 2304;
  int r2 = t - zz*2304;
  int yy = r2 / 48;
  int xx = r2 - yy*48;
  int pb = (zz+1)*2500 + (yy+1)*50 + (xx+1);
  const unsigned short* bp[8];
#pragma unroll
  for (int j=0;j<8;j++){
    int e = quad*8 + j;
    int ic = (IC==32) ? e : (e & 15);
    bp[j] = bin + ic*PCH + pb;
  }
  const int rq = (IC==32) ? 0 : (quad >> 1);
  f32x4 acc = {0.f, 0.f, 0.f, 0.f};
#pragma unroll
  for (int kb=0; kb<NKB; kb++){
    bf16x8 af = *reinterpret_cast<const bf16x8*>(wA + (size_t)((kb*4+quad)*16 + n)*8);
    int off;
    if (IC==32) off = off3c(kb);
    else        off = rq ? off3c(2*kb+1) : off3c(2*kb);
    bf16x8 bf;
#pragma unroll
    for (int j=0;j<8;j++) bf[j] = (short)bp[j][off];
    acc = __builtin_amdgcn_mfma_f32_16x16x32_bf16(af, bf, acc, 0, 0, 0);
  }
  float vs[4];
#pragma unroll
  for (int reg=0; reg<4; reg++){
    int m = quad*4 + reg;
    float v = acc[reg] + bias[m];
    out[m*L_TOT + t] = v;
    vs[reg] = v;
  }
#pragma unroll
  for (int reg=0; reg<4; reg++){
    float a = vs[reg], b2 = vs[reg]*vs[reg];
#pragma unroll
    for (int o=1; o<16; o<<=1){ a += __shfl_xor(a,o); b2 += __shfl_xor(b2,o); }
    if (n == 0){
      atomicAdd(&sred[quad*4+reg], a);
      atomicAdd(&sred[16 + quad*4+reg], b2);
    }
  }
  __syncthreads();
  if (threadIdx.x < 16){
    atomicAdd(&stats[2*threadIdx.x],   sred[threadIdx.x]);
    atomicAdd(&stats[2*threadIdx.x+1], sred[16+threadIdx.x]);
  }
}

// ---------------- BN normalize, float4 --------------------------------------------
__global__ void k_bn_norm4(const float* __restrict__ raw, const float* __restrict__ stats,
                           const float* __restrict__ g, const float* __restrict__ b,
                           float* __restrict__ out) {
  int i = blockIdx.x*256 + threadIdx.x;         // over 16*L_TOT/4
  int c = i / (L_TOT/4);
  int tq = i - c*(L_TOT/4);
  float m = stats[2*c]*(1.f/L_TOT);
  float v = stats[2*c+1]*(1.f/L_TOT) - m*m;
  float sc = rsqrtf(v+BN_EPS)*g[c];
  float bs = b[c] - m*sc;
  float4 x = *reinterpret_cast<const float4*>(raw + c*L_TOT + tq*4);
  float4 o = make_float4(x.x*sc+bs, x.y*sc+bs, x.z*sc+bs, x.w*sc+bs);
  *reinterpret_cast<float4*>(out + c*L_TOT + tq*4) = o;
}

// =================================================================================
extern "C" void kernel_launch(void* const* d_in, const int* in_sizes, int n_in,
                              void* d_out, int out_size, void* d_ws, size_t ws_size,
                              hipStream_t stream) {
  const float* l        = (const float*)d_in[0];
  const float* s        = (const float*)d_in[1];
  const float* m1_ln_w  = (const float*)d_in[2];
  const float* m1_ln_b  = (const float*)d_in[3];
  const float* m1_in_w  = (const float*)d_in[4];
  const float* m1_cw    = (const float*)d_in[5];
  const float* m1_cb    = (const float*)d_in[6];
  const float* m1_xp_w  = (const float*)d_in[7];
  const float* m1_dt_w  = (const float*)d_in[8];
  const float* m1_dt_b  = (const float*)d_in[9];
  const float* m1_Alog  = (const float*)d_in[10];
  const float* m1_D     = (const float*)d_in[11];
  const float* m1_out_w = (const float*)d_in[12];
  const float* m2_ln_w  = (const float*)d_in[13];
  const float* m2_ln_b  = (const float*)d_in[14];
  const float* m2_in_w  = (const float*)d_in[15];
  const float* m2_cw    = (const float*)d_in[16];
  const float* m2_cb    = (const float*)d_in[17];
  const float* m2_xp_w  = (const float*)d_in[18];
  const float* m2_dt_w  = (const float*)d_in[19];
  const float* m2_dt_b  = (const float*)d_in[20];
  const float* m2_Alog  = (const float*)d_in[21];
  const float* m2_D     = (const float*)d_in[22];
  const float* m2_out_w = (const float*)d_in[23];
  const float* c1_w     = (const float*)d_in[24];
  const float* c1_b     = (const float*)d_in[25];
  const float* bn1_g    = (const float*)d_in[26];
  const float* bn1_b    = (const float*)d_in[27];
  const float* c2_w     = (const float*)d_in[28];
  const float* c2_b     = (const float*)d_in[29];
  const float* bn2_g    = (const float*)d_in[30];
  const float* bn2_b    = (const float*)d_in[31];

  float* ws = (float*)d_ws;
  const size_t L = L_TOT;
  float* xc1      = ws;               // 64L
  float* z1       = ws + 64*L;        // 64L
  float* B1       = ws + 128*L;       // 16L   (reused by stage 2)
  float* C1       = ws + 144*L;       // 16L   (reused by stage 2)
  float* dtp1     = ws + 160*L;       // 2L    (reused by stage 2)
  float* conv1raw = ws + 162*L;       // 16L
  float* xc2      = ws + 178*L;       // 32L
  float* z2       = ws + 210*L;       // 32L
  float* conv2raw = ws + 242*L;       // 16L
  float* aggA     = ws + 258*L;       // 786432
  float* aggB     = aggA + 786432;
  float* carry    = aggB + 786432;    // ends at 322L
  float* stats1   = ws + 322*L;       // 32
  float* stats2   = stats1 + 32;      // 32
  unsigned short* bfin = (unsigned short*)(ws + 323*L);   // 32ch * PCH bf16
  unsigned short* wA1  = (unsigned short*)(ws + 343*L);   // 13824
  unsigned short* wA2  = wA1 + 13824;                     // 7168

  // setup: weight pack + zero bfin halo buffer + zero both stats
  k_setup<<<2813,256,0,stream>>>(c1_w, wA1, c2_w, wA2, stats1, (float*)bfin);

  // ================= stage 1: mamba(dim=32, di=64) + conv1 + bn1(stats) ==========
  k_front<32,64,2,false><<<768,256,0,stream>>>(l, s, stats1, bn1_g, bn1_b,
      m1_ln_w, m1_ln_b, m1_in_w, m1_cw, m1_cb, m1_xp_w, m1_dt_w, m1_dt_b, m1_Alog,
      xc1, z1, dtp1, B1, C1, aggA, aggB);
  k_carry<768><<<16,1024,0,stream>>>(aggA, aggB, carry, 1024);
  k_back<32,64,2,0><<<768,256,0,stream>>>(xc1, z1, dtp1, B1, C1,
      m1_dt_w, m1_dt_b, m1_Alog, m1_D, carry, m1_out_w, l, s,
      stats1, bn1_g, bn1_b, bfin);
  k_conv_mfma<32><<<576,256,0,stream>>>(bfin, wA1, c1_b, conv1raw, stats1);

  // ================= stage 2: mamba(dim=16, di=32) + conv2 + bn2 =================
  k_front<16,32,1,true><<<768,256,0,stream>>>(conv1raw, conv1raw, stats1, bn1_g, bn1_b,
      m2_ln_w, m2_ln_b, m2_in_w, m2_cw, m2_cb, m2_xp_w, m2_dt_w, m2_dt_b, m2_Alog,
      xc2, z2, dtp1, B1, C1, aggA, aggB);
  k_carry<768><<<8,1024,0,stream>>>(aggA, aggB, carry, 512);
  k_back<16,32,1,1><<<768,256,0,stream>>>(xc2, z2, dtp1, B1, C1,
      m2_dt_w, m2_dt_b, m2_Alog, m2_D, carry, m2_out_w, conv1raw, conv1raw,
      stats1, bn1_g, bn1_b, bfin);
  k_conv_mfma<16><<<576,256,0,stream>>>(bfin, wA2, c2_b, conv2raw, stats2);
  k_bn_norm4<<<576,256,0,stream>>>(conv2raw, stats2, bn2_g, bn2_b, (float*)d_out);
}

// Round 7
// 300.211 us; speedup vs baseline: 2.0318x; 1.0471x over previous
//
#include <hip/hip_runtime.h>
#include <math.h>

#define L_TOT 36864
#define BN_EPS 1e-5f
#define PCH 45000   // padded channel stride: 18*50*50

typedef __attribute__((ext_vector_type(8))) short bf16x8;
typedef __attribute__((ext_vector_type(4))) float f32x4;

__device__ __forceinline__ float fsigmoid(float x){ return 1.f/(1.f+__expf(-x)); }
__device__ __forceinline__ float fsoftplus(float x){
  float e = __expf(x);
  return (x>20.f)? x : __logf(1.f+e);
}
__device__ __forceinline__ unsigned short f2bf(float x){
  union { float f; unsigned u; } cv; cv.f = x;
  unsigned r = (cv.u + 0x7FFFu + ((cv.u>>16)&1u)) >> 16;
  return (unsigned short)r;
}
__host__ __device__ constexpr int off3c(int r){
  return (r>=27) ? 0 : ((r/9)-1)*2500 + (((r%9)/3)-1)*50 + ((r%3)-1);
}

// ---------------- setup: pack conv weights + zero bf16 halo buffer + zero stats ---
__global__ void k_setup(const float* __restrict__ w1, unsigned short* __restrict__ wA1,
                        const float* __restrict__ w2, unsigned short* __restrict__ wA2,
                        float* __restrict__ stats, float* __restrict__ bfz) {
  int b = blockIdx.x, tid = threadIdx.x;
  int idx = b*256 + tid;
  if (idx < 16*PCH) bfz[idx] = 0.f;     // zero all 32 bf16 channels (as 32-bit words)
  if (b < 4){
    int k = b*256 + tid;
    if (k < 864){
      int ic = k & 31, r = k >> 5;
      for (int m=0;m<16;m++){
        float v = (r < 27) ? w1[m*32*27 + ic*27 + r] : 0.f;
        wA1[(((k>>3)*16) + m)*8 + (k&7)] = f2bf(v);
      }
    }
  } else if (b < 6){
    int k = (b-4)*256 + tid;
    if (k < 448){
      int ic = k & 15, r = k >> 4;
      for (int m=0;m<16;m++){
        float v = (r < 27) ? w2[m*16*27 + ic*27 + r] : 0.f;
        wA2[(((k>>3)*16) + m)*8 + (k&7)] = f2bf(v);
      }
    }
  } else if (b == 6){
    if (tid < 64) stats[tid] = 0.f;
  }
}

// =================================================================================
// k_front: fused LN (+BN-on-read) + in-proj + causal dwconv/SiLU + x-proj + dt +
//          pass1 chunk aggregates.  One block = one chunk of 48 timesteps.
// Region0 (DI*64 floats) is time-aliased: SX -> xs(+halo) -> dt.
// P2 in-proj: simple row-serial loop (round-1 form; compiler pipelines it best).
// =================================================================================
template<int DIM, int DI, int DTR, bool DOBN>
__global__ __launch_bounds__(256) void k_front(
    const float* __restrict__ x0, const float* __restrict__ x1,
    const float* __restrict__ bstats, const float* __restrict__ bg, const float* __restrict__ bbp,
    const float* __restrict__ lnw, const float* __restrict__ lnb,
    const float* __restrict__ inw,
    const float* __restrict__ cw, const float* __restrict__ cb,
    const float* __restrict__ xpw,
    const float* __restrict__ dtw, const float* __restrict__ dtb,
    const float* __restrict__ Alog,
    float* __restrict__ xcg, float* __restrict__ zg,
    float* __restrict__ dtpg, float* __restrict__ Bg, float* __restrict__ Cg,
    float* __restrict__ aggA, float* __restrict__ aggB)
{
  constexpr int TCH  = 48;
  constexpr int ROWS = DTR + 32;
  constexpr int NSH  = 256/DI;        // threads per d-channel in scan
  constexpr int SPB  = 16/NSH;        // states per thread
  constexpr int CH   = DI*16;
  constexpr int R0SZ = DI*64;         // region0: SX (DIM*64) / xs+halo (DI*64) / dt (DI*49)
  constexpr int O_SXC = R0SZ;         // DI*49
  constexpr int O_SB  = O_SXC + DI*49;// 16*49
  constexpr int O_SC  = O_SB + 16*49; // 16*49
  constexpr int O_DTP = O_SC + 16*49; // DTR*48
  constexpr int SMEM  = O_DTP + DTR*48 + 64;
  __shared__ float sm[SMEM];

  const int tid   = threadIdx.x;
  const int chunk = blockIdx.x;
  const int t0    = chunk*TCH;

  // ---- P0: load x (+optional BN-normalize) into region0; cols 0..50 = t0-3..t0+47
  for (int idx = tid; idx < DIM*64; idx += 256){
    int c = idx >> 6, i2 = idx & 63;
    int t = t0 - 3 + i2;
    float v = 0.f;
    if (i2 < 51 && t >= 0){
      if constexpr (DOBN){
        float raw = x0[c*L_TOT + t];
        float bm = bstats[2*c]*(1.f/L_TOT);
        float bv = bstats[2*c+1]*(1.f/L_TOT) - bm*bm;
        v = (raw - bm)*rsqrtf(bv+BN_EPS)*bg[c] + bbp[c];
      } else {
        v = (c < 16) ? x0[c*L_TOT + t] : x1[(c-16)*L_TOT + t];
      }
    }
    sm[idx] = v;
  }
  __syncthreads();

  // ---- P1: LayerNorm per column, in place (cols >=51 all-zero, stay finite)
  if (tid < 64){
    float s = 0.f, s2 = 0.f;
#pragma unroll
    for (int c = 0; c < DIM; c++){
      float v = sm[c*64 + tid];
      s += v; s2 += v*v;
    }
    float m  = s*(1.f/DIM);
    float var = s2*(1.f/DIM) - m*m;
    float rs = rsqrtf(var + BN_EPS);
#pragma unroll
    for (int c = 0; c < DIM; c++){
      float v = sm[c*64 + tid];
      sm[c*64 + tid] = (v-m)*rs*lnw[c] + lnb[c];
    }
  }
  __syncthreads();

  // ---- P2: in-proj (row-serial).  xs rows -> region0 (over SX), z rows -> global
  const int i   = tid & 63;
  const int r0w = __builtin_amdgcn_readfirstlane(tid >> 6);
  {
    float xn[DIM];
#pragma unroll
    for (int c = 0; c < DIM; c++) xn[c] = sm[c*64 + i];
    __syncthreads();                   // everyone finished reading SX; region0 reusable
    for (int r = r0w; r < 2*DI; r += 4){
      float acc = 0.f;
#pragma unroll
      for (int c = 0; c < DIM; c++) acc += xn[c]*inw[r*DIM + c];
      if (r < DI){
        if (i < 51) sm[r*64 + i] = (t0 == 0 && i < 3) ? 0.f : acc;
      } else {
        if (i >= 3 && i < 51) zg[(r-DI)*L_TOT + t0 + i - 3] = acc;
      }
    }
  }
  __syncthreads();

  // ---- P3: causal depthwise conv (kw=4) + SiLU -> SXC
  for (int idx = tid; idx < DI*48; idx += 256){
    int d = idx / 48, j = idx - d*48;
    const float* xr = &sm[d*64 + j];     // xr[k] = xs[t-3+k]
    float acc = cb[d] + cw[d*4+0]*xr[0] + cw[d*4+1]*xr[1]
                      + cw[d*4+2]*xr[2] + cw[d*4+3]*xr[3];
    sm[O_SXC + d*49 + j] = acc * fsigmoid(acc);
  }
  __syncthreads();

  // ---- P4: x-proj -> dtp | B | C
  {
    constexpr int NR = (ROWS + 3) / 4;
    float acc[NR];
#pragma unroll
    for (int rr = 0; rr < NR; rr++) acc[rr] = 0.f;
    for (int db = 0; db < DI; db += 16){
      float xcol[16];
#pragma unroll
      for (int k = 0; k < 16; k++) xcol[k] = sm[O_SXC + (db+k)*49 + i];
#pragma unroll
      for (int rr = 0; rr < NR; rr++){
        int r = r0w + rr*4;
        if (r < ROWS){
          float a2 = 0.f;
#pragma unroll
          for (int k = 0; k < 16; k++) a2 += xcol[k]*xpw[r*DI + db + k];
          acc[rr] += a2;
        }
      }
    }
    if (i < 48){
#pragma unroll
      for (int rr = 0; rr < NR; rr++){
        int r = r0w + rr*4;
        if (r < ROWS){
          if (r < DTR)          sm[O_DTP + r*48 + i] = acc[rr];
          else if (r < DTR+16)  sm[O_SB + (r-DTR)*49 + i] = acc[rr];
          else                  sm[O_SC + (r-DTR-16)*49 + i] = acc[rr];
        }
      }
    }
  }
  __syncthreads();

  // ---- P5: dt = softplus(dtb + dtw*dtp) -> region0 (xs dead)
  for (int idx = tid; idx < DI*48; idx += 256){
    int d = idx / 48, j = idx - d*48;
    float pre = dtb[d] + dtw[d*DTR]*sm[O_DTP + j];
    if (DTR > 1) pre += dtw[d*DTR + DTR-1]*sm[O_DTP + (DTR-1)*48 + j];
    sm[d*49 + j] = fsoftplus(pre);
  }
  __syncthreads();

  // ---- P6: spill xc/dtp/B/C to global (stores fly during pass1 compute)
  for (int idx = tid; idx < DI*12; idx += 256){
    int d = idx / 12, q = idx - d*12;
    float4 v = make_float4(sm[O_SXC + d*49 + q*4+0], sm[O_SXC + d*49 + q*4+1],
                           sm[O_SXC + d*49 + q*4+2], sm[O_SXC + d*49 + q*4+3]);
    *reinterpret_cast<float4*>(xcg + d*L_TOT + t0 + q*4) = v;
  }
  for (int idx = tid; idx < ROWS*48; idx += 256){
    int r = idx / 48, j = idx - r*48;
    if (r < DTR)         dtpg[r*L_TOT + t0 + j]        = sm[O_DTP + r*48 + j];
    else if (r < DTR+16) Bg[(r-DTR)*L_TOT + t0 + j]    = sm[O_SB + (r-DTR)*49 + j];
    else                 Cg[(r-DTR-16)*L_TOT + t0 + j] = sm[O_SC + (r-DTR-16)*49 + j];
  }

  // ---- P7: pass1 scan -> per-chunk (A,B) aggregates
  {
    const int d  = tid / NSH;
    const int sh = tid - d*NSH;
    float Av[SPB], Ar[SPB], Br[SPB];
#pragma unroll
    for (int j = 0; j < SPB; j++){
      Av[j] = -__expf(Alog[d*16 + sh*SPB + j]);
      Ar[j] = 1.f; Br[j] = 0.f;
    }
    for (int t = 0; t < TCH; t++){
      float dtv = sm[d*49 + t];
      float bb2 = dtv * sm[O_SXC + d*49 + t];
#pragma unroll
      for (int j = 0; j < SPB; j++){
        float a2 = __expf(dtv*Av[j]);
        Ar[j] *= a2;
        Br[j] = a2*Br[j] + bb2*sm[O_SB + (sh*SPB+j)*49 + t];
      }
    }
    const int o = chunk*CH + tid*SPB;
    if constexpr (SPB == 4){
      *reinterpret_cast<float4*>(&aggA[o]) = make_float4(Ar[0],Ar[1],Ar[2],Ar[3]);
      *reinterpret_cast<float4*>(&aggB[o]) = make_float4(Br[0],Br[1],Br[2],Br[3]);
    } else {
      *reinterpret_cast<float2*>(&aggA[o]) = make_float2(Ar[0],Ar[1]);
      *reinterpret_cast<float2*>(&aggB[o]) = make_float2(Br[0],Br[1]);
    }
  }
}

// ---------------- parallel scan over chunk aggregates -> carries ------------------
// 16 channels x 16 segments per 256-thread block; grid = CH/16 blocks (4-8x more
// CUs in flight than the old 64ch x 1024-thread layout; same serial depth).
template<int NCH>
__global__ __launch_bounds__(256) void k_carry(const float* __restrict__ aggA,
                        const float* __restrict__ aggB,
                        float* __restrict__ carry, int CH) {
  constexpr int SEG = NCH/16;         // 48 chunks per segment
  const int chl = threadIdx.x & 15;
  const int seg = threadIdx.x >> 4;
  const int ch  = blockIdx.x*16 + chl;
  const int c0  = seg*SEG;
  float a = 1.f, b = 0.f;
  for (int cb=c0; cb<c0+SEG; cb+=8){
    float av[8], bv[8];
#pragma unroll
    for (int k=0;k<8;k++){ av[k]=aggA[(cb+k)*CH+ch]; bv[k]=aggB[(cb+k)*CH+ch]; }
#pragma unroll
    for (int k=0;k<8;k++){ a = a*av[k]; b = av[k]*b + bv[k]; }
  }
  __shared__ float sa[16][17], sb[16][17];
  sa[seg][chl]=a; sb[seg][chl]=b;
  __syncthreads();
  if (threadIdx.x < 16){
    float pa=1.f, pb=0.f;
    for (int g=0; g<16; g++){
      float ca=sa[g][threadIdx.x], cb2=sb[g][threadIdx.x];
      sa[g][threadIdx.x]=pa; sb[g][threadIdx.x]=pb;
      float na = pa*ca;
      float nb = ca*pb + cb2;
      pa=na; pb=nb;
    }
  }
  __syncthreads();
  float h = sb[seg][chl];
  for (int cb=c0; cb<c0+SEG; cb+=8){
    float av[8], bv[8];
#pragma unroll
    for (int k=0;k<8;k++){ av[k]=aggA[(cb+k)*CH+ch]; bv[k]=aggB[(cb+k)*CH+ch]; }
#pragma unroll
    for (int k=0;k<8;k++){ carry[(cb+k)*CH+ch]=h; h = av[k]*h + bv[k]; }
  }
}

// =================================================================================
// k_back: fused pass2 scan + z-gate + out-proj + residual -> bf16 padded layout.
// =================================================================================
template<int DIM, int DI, int DTR, int RES>
__global__ __launch_bounds__(256) void k_back(
    const float* __restrict__ xcg, const float* __restrict__ zg,
    const float* __restrict__ dtpg, const float* __restrict__ Bg, const float* __restrict__ Cg,
    const float* __restrict__ dtw, const float* __restrict__ dtb,
    const float* __restrict__ Alog, const float* __restrict__ Dp,
    const float* __restrict__ carry,
    const float* __restrict__ ow,
    const float* __restrict__ r0src, const float* __restrict__ r1src,
    const float* __restrict__ bstats, const float* __restrict__ bg, const float* __restrict__ bbp,
    unsigned short* __restrict__ rp)
{
  constexpr int TCH = 48;
  constexpr int NSH = 256/DI;
  constexpr int SPB = 16/NSH;
  constexpr int O_SXC = 0;               // DI*49
  constexpr int O_SDT = O_SXC + DI*49;   // DI*49
  constexpr int O_SB  = O_SDT + DI*49;   // 16*49
  constexpr int O_SC  = O_SB + 16*49;    // 16*49
  constexpr int O_SY  = O_SC + 16*49;    // DI*49
  constexpr int O_DTP = O_SY + DI*49;    // DTR*48
  constexpr int SMEM  = O_DTP + DTR*48 + 64;
  __shared__ float sm[SMEM];
  const int tid   = threadIdx.x;
  const int chunk = blockIdx.x;
  const int t0    = chunk*TCH;

  // ---- load xc / B / C / dtp
  for (int idx = tid; idx < DI*12; idx += 256){
    int d = idx / 12, q = idx - d*12;
    float4 v = *reinterpret_cast<const float4*>(xcg + d*L_TOT + t0 + q*4);
    sm[O_SXC + d*49 + q*4+0] = v.x; sm[O_SXC + d*49 + q*4+1] = v.y;
    sm[O_SXC + d*49 + q*4+2] = v.z; sm[O_SXC + d*49 + q*4+3] = v.w;
  }
  for (int idx = tid; idx < (DTR+32)*48; idx += 256){
    int r = idx / 48, j = idx - r*48;
    if (r < DTR)         sm[O_DTP + r*48 + j]        = dtpg[r*L_TOT + t0 + j];
    else if (r < DTR+16) sm[O_SB + (r-DTR)*49 + j]   = Bg[(r-DTR)*L_TOT + t0 + j];
    else                 sm[O_SC + (r-DTR-16)*49 + j]= Cg[(r-DTR-16)*L_TOT + t0 + j];
  }
  __syncthreads();
  // ---- dt = softplus(dtb + dtw*dtp)
  for (int idx = tid; idx < DI*48; idx += 256){
    int d = idx / 48, j = idx - d*48;
    float pre = dtb[d] + dtw[d*DTR]*sm[O_DTP + j];
    if (DTR > 1) pre += dtw[d*DTR + DTR-1]*sm[O_DTP + 48 + j];
    sm[O_SDT + d*49 + j] = fsoftplus(pre);
  }
  __syncthreads();

  // ---- pass2 scan: h update + y = sum_s h*C + xc*D -> SY
  {
    const int d  = tid / NSH;
    const int sh = tid - d*NSH;
    float Av[SPB], h[SPB];
#pragma unroll
    for (int j = 0; j < SPB; j++){
      Av[j] = -__expf(Alog[d*16 + sh*SPB + j]);
      h[j]  = carry[chunk*(DI*16) + tid*SPB + j];
    }
    const float Dv = Dp[d];
    for (int t = 0; t < TCH; t++){
      float dtv = sm[O_SDT + d*49 + t];
      float xcv = sm[O_SXC + d*49 + t];
      float bb2 = dtv*xcv;
      float p = 0.f;
#pragma unroll
      for (int j = 0; j < SPB; j++){
        float a2 = __expf(dtv*Av[j]);
        h[j] = a2*h[j] + bb2*sm[O_SB + (sh*SPB+j)*49 + t];
        p += h[j]*sm[O_SC + (sh*SPB+j)*49 + t];
      }
#pragma unroll
      for (int o = 1; o < NSH; o <<= 1) p += __shfl_xor(p, o);
      if (sh == 0) sm[O_SY + d*49 + t] = p + xcv*Dv;
    }
  }
  __syncthreads();
  // ---- gate: y *= silu(z)   (z streamed from global, never staged)
  for (int idx = tid; idx < DI*12; idx += 256){
    int d = idx / 12, q = idx - d*12;
    float4 zv = *reinterpret_cast<const float4*>(zg + d*L_TOT + t0 + q*4);
    sm[O_SY + d*49 + q*4+0] *= zv.x*fsigmoid(zv.x);
    sm[O_SY + d*49 + q*4+1] *= zv.y*fsigmoid(zv.y);
    sm[O_SY + d*49 + q*4+2] *= zv.z*fsigmoid(zv.z);
    sm[O_SY + d*49 + q*4+3] *= zv.w*fsigmoid(zv.w);
  }
  __syncthreads();

  // ---- out-proj + residual -> padded bf16 conv input
  {
    const int col = tid & 63;
    const int r0w = __builtin_amdgcn_readfirstlane(tid >> 6);
    constexpr int NO = DIM/4;
    float acc[NO];
#pragma unroll
    for (int rr = 0; rr < NO; rr++) acc[rr] = 0.f;
    for (int db = 0; db < DI; db += 16){
      float ycol[16];
#pragma unroll
      for (int k = 0; k < 16; k++) ycol[k] = sm[O_SY + (db+k)*49 + col];
#pragma unroll
      for (int rr = 0; rr < NO; rr++){
        int r = r0w + rr*4;
        float a2 = 0.f;
#pragma unroll
        for (int k = 0; k < 16; k++) a2 += ycol[k]*ow[r*DI + db + k];
        acc[rr] += a2;
      }
    }
    if (col < 48){
      const int t  = t0 + col;
      const int zz = chunk / 48, yy = chunk - zz*48;     // 48 cols = one (zz,yy) row
      const int pb = (zz+1)*2500 + (yy+1)*50 + (col+1);
#pragma unroll
      for (int rr = 0; rr < NO; rr++){
        int r = r0w + rr*4;
        float res;
        if (RES == 0){
          res = (r < 16) ? r0src[r*L_TOT + t] : r1src[(r-16)*L_TOT + t];
        } else {
          float bm = bstats[2*r]*(1.f/L_TOT);
          float bv = bstats[2*r+1]*(1.f/L_TOT) - bm*bm;
          res = (r0src[r*L_TOT + t] - bm)*rsqrtf(bv+BN_EPS)*bg[r] + bbp[r];
        }
        rp[r*PCH + pb] = f2bf(acc[rr] + res);
      }
    }
  }
}

// ---------------- conv3d via MFMA implicit GEMM + fused BN partial sums -----------
template<int IC>
__global__ __launch_bounds__(256) void k_conv_mfma(const unsigned short* __restrict__ bin,
                         const unsigned short* __restrict__ wA,
                         const float* __restrict__ bias, float* __restrict__ out,
                         float* __restrict__ stats) {
  constexpr int NKB = (IC==32) ? 27 : 14;
  __shared__ float sred[32];
  if (threadIdx.x < 32) sred[threadIdx.x] = 0.f;
  __syncthreads();
  const int lane = threadIdx.x & 63;
  const int n = lane & 15, quad = lane >> 4;
  const int tile = blockIdx.x*4 + (threadIdx.x >> 6);
  const int t = tile*16 + n;
  int zz = t / 2304;
  int r2 = t - zz*2304;
  int yy = r2 / 48;
  int xx = r2 - yy*48;
  int pb = (zz+1)*2500 + (yy+1)*50 + (xx+1);
  const unsigned short* bp[8];
#pragma unroll
  for (int j=0;j<8;j++){
    int e = quad*8 + j;
    int ic = (IC==32) ? e : (e & 15);
    bp[j] = bin + ic*PCH + pb;
  }
  const int rq = (IC==32) ? 0 : (quad >> 1);
  f32x4 acc = {0.f, 0.f, 0.f, 0.f};
#pragma unroll
  for (int kb=0; kb<NKB; kb++){
    bf16x8 af = *reinterpret_cast<const bf16x8*>(wA + (size_t)((kb*4+quad)*16 + n)*8);
    int off;
    if (IC==32) off = off3c(kb);
    else        off = rq ? off3c(2*kb+1) : off3c(2*kb);
    bf16x8 bf;
#pragma unroll
    for (int j=0;j<8;j++) bf[j] = (short)bp[j][off];
    acc = __builtin_amdgcn_mfma_f32_16x16x32_bf16(af, bf, acc, 0, 0, 0);
  }
  float vs[4];
#pragma unroll
  for (int reg=0; reg<4; reg++){
    int m = quad*4 + reg;
    float v = acc[reg] + bias[m];
    out[m*L_TOT + t] = v;
    vs[reg] = v;
  }
#pragma unroll
  for (int reg=0; reg<4; reg++){
    float a = vs[reg], b2 = vs[reg]*vs[reg];
#pragma unroll
    for (int o=1; o<16; o<<=1){ a += __shfl_xor(a,o); b2 += __shfl_xor(b2,o); }
    if (n == 0){
      atomicAdd(&sred[quad*4+reg], a);
      atomicAdd(&sred[16 + quad*4+reg], b2);
    }
  }
  __syncthreads();
  if (threadIdx.x < 16){
    atomicAdd(&stats[2*threadIdx.x],   sred[threadIdx.x]);
    atomicAdd(&stats[2*threadIdx.x+1], sred[16+threadIdx.x]);
  }
}

// ---------------- BN normalize, float4 --------------------------------------------
__global__ void k_bn_norm4(const float* __restrict__ raw, const float* __restrict__ stats,
                           const float* __restrict__ g, const float* __restrict__ b,
                           float* __restrict__ out) {
  int i = blockIdx.x*256 + threadIdx.x;         // over 16*L_TOT/4
  int c = i / (L_TOT/4);
  int tq = i - c*(L_TOT/4);
  float m = stats[2*c]*(1.f/L_TOT);
  float v = stats[2*c+1]*(1.f/L_TOT) - m*m;
  float sc = rsqrtf(v+BN_EPS)*g[c];
  float bs = b[c] - m*sc;
  float4 x = *reinterpret_cast<const float4*>(raw + c*L_TOT + tq*4);
  float4 o = make_float4(x.x*sc+bs, x.y*sc+bs, x.z*sc+bs, x.w*sc+bs);
  *reinterpret_cast<float4*>(out + c*L_TOT + tq*4) = o;
}

// =================================================================================
extern "C" void kernel_launch(void* const* d_in, const int* in_sizes, int n_in,
                              void* d_out, int out_size, void* d_ws, size_t ws_size,
                              hipStream_t stream) {
  const float* l        = (const float*)d_in[0];
  const float* s        = (const float*)d_in[1];
  const float* m1_ln_w  = (const float*)d_in[2];
  const float* m1_ln_b  = (const float*)d_in[3];
  const float* m1_in_w  = (const float*)d_in[4];
  const float* m1_cw    = (const float*)d_in[5];
  const float* m1_cb    = (const float*)d_in[6];
  const float* m1_xp_w  = (const float*)d_in[7];
  const float* m1_dt_w  = (const float*)d_in[8];
  const float* m1_dt_b  = (const float*)d_in[9];
  const float* m1_Alog  = (const float*)d_in[10];
  const float* m1_D     = (const float*)d_in[11];
  const float* m1_out_w = (const float*)d_in[12];
  const float* m2_ln_w  = (const float*)d_in[13];
  const float* m2_ln_b  = (const float*)d_in[14];
  const float* m2_in_w  = (const float*)d_in[15];
  const float* m2_cw    = (const float*)d_in[16];
  const float* m2_cb    = (const float*)d_in[17];
  const float* m2_xp_w  = (const float*)d_in[18];
  const float* m2_dt_w  = (const float*)d_in[19];
  const float* m2_dt_b  = (const float*)d_in[20];
  const float* m2_Alog  = (const float*)d_in[21];
  const float* m2_D     = (const float*)d_in[22];
  const float* m2_out_w = (const float*)d_in[23];
  const float* c1_w     = (const float*)d_in[24];
  const float* c1_b     = (const float*)d_in[25];
  const float* bn1_g    = (const float*)d_in[26];
  const float* bn1_b    = (const float*)d_in[27];
  const float* c2_w     = (const float*)d_in[28];
  const float* c2_b     = (const float*)d_in[29];
  const float* bn2_g    = (const float*)d_in[30];
  const float* bn2_b    = (const float*)d_in[31];

  float* ws = (float*)d_ws;
  const size_t L = L_TOT;
  float* xc1      = ws;               // 64L
  float* z1       = ws + 64*L;        // 64L
  float* B1       = ws + 128*L;       // 16L   (reused by stage 2)
  float* C1       = ws + 144*L;       // 16L   (reused by stage 2)
  float* dtp1     = ws + 160*L;       // 2L    (reused by stage 2)
  float* conv1raw = ws + 162*L;       // 16L
  float* xc2      = ws + 178*L;       // 32L
  float* z2       = ws + 210*L;       // 32L
  float* conv2raw = ws + 242*L;       // 16L
  float* aggA     = ws + 258*L;       // 786432
  float* aggB     = aggA + 786432;
  float* carry    = aggB + 786432;    // ends at 322L
  float* stats1   = ws + 322*L;       // 32
  float* stats2   = stats1 + 32;      // 32
  unsigned short* bfin = (unsigned short*)(ws + 323*L);   // 32ch * PCH bf16
  unsigned short* wA1  = (unsigned short*)(ws + 343*L);   // 13824
  unsigned short* wA2  = wA1 + 13824;                     // 7168

  // setup: weight pack + zero bfin halo buffer + zero both stats
  k_setup<<<2813,256,0,stream>>>(c1_w, wA1, c2_w, wA2, stats1, (float*)bfin);

  // ================= stage 1: mamba(dim=32, di=64) + conv1 + bn1(stats) ==========
  k_front<32,64,2,false><<<768,256,0,stream>>>(l, s, stats1, bn1_g, bn1_b,
      m1_ln_w, m1_ln_b, m1_in_w, m1_cw, m1_cb, m1_xp_w, m1_dt_w, m1_dt_b, m1_Alog,
      xc1, z1, dtp1, B1, C1, aggA, aggB);
  k_carry<768><<<64,256,0,stream>>>(aggA, aggB, carry, 1024);
  k_back<32,64,2,0><<<768,256,0,stream>>>(xc1, z1, dtp1, B1, C1,
      m1_dt_w, m1_dt_b, m1_Alog, m1_D, carry, m1_out_w, l, s,
      stats1, bn1_g, bn1_b, bfin);
  k_conv_mfma<32><<<576,256,0,stream>>>(bfin, wA1, c1_b, conv1raw, stats1);

  // ================= stage 2: mamba(dim=16, di=32) + conv2 + bn2 =================
  k_front<16,32,1,true><<<768,256,0,stream>>>(conv1raw, conv1raw, stats1, bn1_g, bn1_b,
      m2_ln_w, m2_ln_b, m2_in_w, m2_cw, m2_cb, m2_xp_w, m2_dt_w, m2_dt_b, m2_Alog,
      xc2, z2, dtp1, B1, C1, aggA, aggB);
  k_carry<768><<<32,256,0,stream>>>(aggA, aggB, carry, 512);
  k_back<16,32,1,1><<<768,256,0,stream>>>(xc2, z2, dtp1, B1, C1,
      m2_dt_w, m2_dt_b, m2_Alog, m2_D, carry, m2_out_w, conv1raw, conv1raw,
      stats1, bn1_g, bn1_b, bfin);
  k_conv_mfma<16><<<576,256,0,stream>>>(bfin, wA2, c2_b, conv2raw, stats2);
  k_bn_norm4<<<576,256,0,stream>>>(conv2raw, stats2, bn2_g, bn2_b, (float*)d_out);
}

// Round 9
// 290.221 us; speedup vs baseline: 2.1017x; 1.0344x over previous
//
#include <hip/hip_runtime.h>
#include <math.h>

#define L_TOT 36864
#define BN_EPS 1e-5f
#define PCH 45000   // padded channel stride: 18*50*50

typedef __attribute__((ext_vector_type(8))) short bf16x8;
typedef __attribute__((ext_vector_type(4))) float f32x4;

__device__ __forceinline__ float fsigmoid(float x){ return 1.f/(1.f+__expf(-x)); }
__device__ __forceinline__ float fsoftplus(float x){
  float e = __expf(x);
  return (x>20.f)? x : __logf(1.f+e);
}
__device__ __forceinline__ unsigned short f2bf(float x){
  union { float f; unsigned u; } cv; cv.f = x;
  unsigned r = (cv.u + 0x7FFFu + ((cv.u>>16)&1u)) >> 16;
  return (unsigned short)r;
}
__host__ __device__ constexpr int off3c(int r){
  return (r>=27) ? 0 : ((r/9)-1)*2500 + (((r%9)/3)-1)*50 + ((r%3)-1);
}

// =================================================================================
// k_front: fused LN (+BN-on-read) + in-proj + causal dwconv/SiLU + x-proj + dt +
//          pass1 chunk aggregates.  One block = one chunk of 48 timesteps.
// Region0 (DI*64 floats) is time-aliased: SX -> xs(+halo) -> dt.
// SETUP=true (stage 1 only) additionally folds the old k_setup work in:
//   grid-stride zero of the bf16 conv-input halo buffer, conv-weight bf16 packs
//   (blocks 0-5), stats zeroing (block 6). All consumed by LATER kernels only.
// =================================================================================
template<int DIM, int DI, int DTR, bool DOBN, bool SETUP>
__global__ __launch_bounds__(256) void k_front(
    const float* __restrict__ x0, const float* __restrict__ x1,
    const float* __restrict__ bstats, const float* __restrict__ bg, const float* __restrict__ bbp,
    const float* __restrict__ lnw, const float* __restrict__ lnb,
    const float* __restrict__ inw,
    const float* __restrict__ cw, const float* __restrict__ cb,
    const float* __restrict__ xpw,
    const float* __restrict__ dtw, const float* __restrict__ dtb,
    const float* __restrict__ Alog,
    float* __restrict__ xcg, float* __restrict__ zg,
    float* __restrict__ dtpg, float* __restrict__ Bg, float* __restrict__ Cg,
    float* __restrict__ aggA, float* __restrict__ aggB,
    const float* __restrict__ cvw1, unsigned short* __restrict__ wA1,
    const float* __restrict__ cvw2, unsigned short* __restrict__ wA2,
    float* __restrict__ stats, float* __restrict__ bfz)
{
  constexpr int TCH  = 48;
  constexpr int ROWS = DTR + 32;
  constexpr int NSH  = 256/DI;        // threads per d-channel in scan
  constexpr int SPB  = 16/NSH;        // states per thread
  constexpr int CH   = DI*16;
  constexpr int R0SZ = DI*64;         // region0: SX (DIM*64) / xs+halo (DI*64) / dt (DI*49)
  constexpr int O_SXC = R0SZ;         // DI*49
  constexpr int O_SB  = O_SXC + DI*49;// 16*49
  constexpr int O_SC  = O_SB + 16*49; // 16*49
  constexpr int O_DTP = O_SC + 16*49; // DTR*48
  constexpr int SMEM  = O_DTP + DTR*48 + 64;
  __shared__ float sm[SMEM];

  const int tid   = threadIdx.x;
  const int chunk = blockIdx.x;
  const int t0    = chunk*TCH;

  // ---- folded setup (stage 1): outputs consumed only by later kernels ----------
  if constexpr (SETUP){
    for (int idx = blockIdx.x*256 + tid; idx < 16*PCH; idx += 768*256)
      bfz[idx] = 0.f;                          // zero bf16 halo buffer (32-bit words)
    const int b = blockIdx.x;
    if (b < 4){
      int k = b*256 + tid;
      if (k < 864){
        int ic = k & 31, r = k >> 5;
        for (int m=0;m<16;m++){
          float v = (r < 27) ? cvw1[m*32*27 + ic*27 + r] : 0.f;
          wA1[(((k>>3)*16) + m)*8 + (k&7)] = f2bf(v);
        }
      }
    } else if (b < 6){
      int k = (b-4)*256 + tid;
      if (k < 448){
        int ic = k & 15, r = k >> 4;
        for (int m=0;m<16;m++){
          float v = (r < 27) ? cvw2[m*16*27 + ic*27 + r] : 0.f;
          wA2[(((k>>3)*16) + m)*8 + (k&7)] = f2bf(v);
        }
      }
    } else if (b == 6){
      if (tid < 64) stats[tid] = 0.f;
    }
  }

  // ---- P0: load x (+optional BN-normalize) into region0; cols 0..50 = t0-3..t0+47
  for (int idx = tid; idx < DIM*64; idx += 256){
    int c = idx >> 6, i2 = idx & 63;
    int t = t0 - 3 + i2;
    float v = 0.f;
    if (i2 < 51 && t >= 0){
      if constexpr (DOBN){
        float raw = x0[c*L_TOT + t];
        float bm = bstats[2*c]*(1.f/L_TOT);
        float bv = bstats[2*c+1]*(1.f/L_TOT) - bm*bm;
        v = (raw - bm)*rsqrtf(bv+BN_EPS)*bg[c] + bbp[c];
      } else {
        v = (c < 16) ? x0[c*L_TOT + t] : x1[(c-16)*L_TOT + t];
      }
    }
    sm[idx] = v;
  }
  __syncthreads();

  // ---- P1: LayerNorm per column, in place (cols >=51 all-zero, stay finite)
  if (tid < 64){
    float s = 0.f, s2 = 0.f;
#pragma unroll
    for (int c = 0; c < DIM; c++){
      float v = sm[c*64 + tid];
      s += v; s2 += v*v;
    }
    float m  = s*(1.f/DIM);
    float var = s2*(1.f/DIM) - m*m;
    float rs = rsqrtf(var + BN_EPS);
#pragma unroll
    for (int c = 0; c < DIM; c++){
      float v = sm[c*64 + tid];
      sm[c*64 + tid] = (v-m)*rs*lnw[c] + lnb[c];
    }
  }
  __syncthreads();

  // ---- P2: in-proj (row-serial).  xs rows -> region0 (over SX), z rows -> global
  const int i   = tid & 63;
  const int r0w = __builtin_amdgcn_readfirstlane(tid >> 6);
  {
    float xn[DIM];
#pragma unroll
    for (int c = 0; c < DIM; c++) xn[c] = sm[c*64 + i];
    __syncthreads();                   // everyone finished reading SX; region0 reusable
    for (int r = r0w; r < 2*DI; r += 4){
      float acc = 0.f;
#pragma unroll
      for (int c = 0; c < DIM; c++) acc += xn[c]*inw[r*DIM + c];
      if (r < DI){
        if (i < 51) sm[r*64 + i] = (t0 == 0 && i < 3) ? 0.f : acc;
      } else {
        if (i >= 3 && i < 51) zg[(r-DI)*L_TOT + t0 + i - 3] = acc;
      }
    }
  }
  __syncthreads();

  // ---- P3: causal depthwise conv (kw=4) + SiLU -> SXC
  for (int idx = tid; idx < DI*48; idx += 256){
    int d = idx / 48, j = idx - d*48;
    const float* xr = &sm[d*64 + j];     // xr[k] = xs[t-3+k]
    float acc = cb[d] + cw[d*4+0]*xr[0] + cw[d*4+1]*xr[1]
                      + cw[d*4+2]*xr[2] + cw[d*4+3]*xr[3];
    sm[O_SXC + d*49 + j] = acc * fsigmoid(acc);
  }
  __syncthreads();

  // ---- P4: x-proj -> dtp | B | C
  {
    constexpr int NR = (ROWS + 3) / 4;
    float acc[NR];
#pragma unroll
    for (int rr = 0; rr < NR; rr++) acc[rr] = 0.f;
    for (int db = 0; db < DI; db += 16){
      float xcol[16];
#pragma unroll
      for (int k = 0; k < 16; k++) xcol[k] = sm[O_SXC + (db+k)*49 + i];
#pragma unroll
      for (int rr = 0; rr < NR; rr++){
        int r = r0w + rr*4;
        if (r < ROWS){
          float a2 = 0.f;
#pragma unroll
          for (int k = 0; k < 16; k++) a2 += xcol[k]*xpw[r*DI + db + k];
          acc[rr] += a2;
        }
      }
    }
    if (i < 48){
#pragma unroll
      for (int rr = 0; rr < NR; rr++){
        int r = r0w + rr*4;
        if (r < ROWS){
          if (r < DTR)          sm[O_DTP + r*48 + i] = acc[rr];
          else if (r < DTR+16)  sm[O_SB + (r-DTR)*49 + i] = acc[rr];
          else                  sm[O_SC + (r-DTR-16)*49 + i] = acc[rr];
        }
      }
    }
  }
  __syncthreads();

  // ---- P5: dt = softplus(dtb + dtw*dtp) -> region0 (xs dead)
  for (int idx = tid; idx < DI*48; idx += 256){
    int d = idx / 48, j = idx - d*48;
    float pre = dtb[d] + dtw[d*DTR]*sm[O_DTP + j];
    if (DTR > 1) pre += dtw[d*DTR + DTR-1]*sm[O_DTP + (DTR-1)*48 + j];
    sm[d*49 + j] = fsoftplus(pre);
  }
  __syncthreads();

  // ---- P6: spill xc/dtp/B/C to global, all float4 (stores fly during pass1)
  for (int idx = tid; idx < DI*12; idx += 256){
    int d = idx / 12, q = idx - d*12;
    float4 v = make_float4(sm[O_SXC + d*49 + q*4+0], sm[O_SXC + d*49 + q*4+1],
                           sm[O_SXC + d*49 + q*4+2], sm[O_SXC + d*49 + q*4+3]);
    *reinterpret_cast<float4*>(xcg + d*L_TOT + t0 + q*4) = v;
  }
  for (int idx = tid; idx < ROWS*12; idx += 256){
    int r = idx / 12, q = idx - r*12;
    const float* src; float* dst;
    if (r < DTR)        { src = &sm[O_DTP + r*48 + q*4];          dst = dtpg + r*L_TOT + t0 + q*4; }
    else if (r < DTR+16){ src = &sm[O_SB + (r-DTR)*49 + q*4];     dst = Bg + (r-DTR)*L_TOT + t0 + q*4; }
    else                { src = &sm[O_SC + (r-DTR-16)*49 + q*4];  dst = Cg + (r-DTR-16)*L_TOT + t0 + q*4; }
    *reinterpret_cast<float4*>(dst) = make_float4(src[0], src[1], src[2], src[3]);
  }

  // ---- P7: pass1 scan -> per-chunk (A,B) aggregates
  {
    const int d  = tid / NSH;
    const int sh = tid - d*NSH;
    float Av[SPB], Ar[SPB], Br[SPB];
#pragma unroll
    for (int j = 0; j < SPB; j++){
      Av[j] = -__expf(Alog[d*16 + sh*SPB + j]);
      Ar[j] = 1.f; Br[j] = 0.f;
    }
    for (int t = 0; t < TCH; t++){
      float dtv = sm[d*49 + t];
      float bb2 = dtv * sm[O_SXC + d*49 + t];
#pragma unroll
      for (int j = 0; j < SPB; j++){
        float a2 = __expf(dtv*Av[j]);
        Ar[j] *= a2;
        Br[j] = a2*Br[j] + bb2*sm[O_SB + (sh*SPB+j)*49 + t];
      }
    }
    const int o = chunk*CH + tid*SPB;
    if constexpr (SPB == 4){
      *reinterpret_cast<float4*>(&aggA[o]) = make_float4(Ar[0],Ar[1],Ar[2],Ar[3]);
      *reinterpret_cast<float4*>(&aggB[o]) = make_float4(Br[0],Br[1],Br[2],Br[3]);
    } else {
      *reinterpret_cast<float2*>(&aggA[o]) = make_float2(Ar[0],Ar[1]);
      *reinterpret_cast<float2*>(&aggB[o]) = make_float2(Br[0],Br[1]);
    }
  }
}

// ---------------- parallel scan over chunk aggregates -> carries ------------------
// 16 channels x 16 segments per 256-thread block; grid = CH/16 blocks.
template<int NCH>
__global__ __launch_bounds__(256) void k_carry(const float* __restrict__ aggA,
                        const float* __restrict__ aggB,
                        float* __restrict__ carry, int CH) {
  constexpr int SEG = NCH/16;         // 48 chunks per segment
  const int chl = threadIdx.x & 15;
  const int seg = threadIdx.x >> 4;
  const int ch  = blockIdx.x*16 + chl;
  const int c0  = seg*SEG;
  float a = 1.f, b = 0.f;
  for (int cb=c0; cb<c0+SEG; cb+=8){
    float av[8], bv[8];
#pragma unroll
    for (int k=0;k<8;k++){ av[k]=aggA[(cb+k)*CH+ch]; bv[k]=aggB[(cb+k)*CH+ch]; }
#pragma unroll
    for (int k=0;k<8;k++){ a = a*av[k]; b = av[k]*b + bv[k]; }
  }
  __shared__ float sa[16][17], sb[16][17];
  sa[seg][chl]=a; sb[seg][chl]=b;
  __syncthreads();
  if (threadIdx.x < 16){
    float pa=1.f, pb=0.f;
    for (int g=0; g<16; g++){
      float ca=sa[g][threadIdx.x], cb2=sb[g][threadIdx.x];
      sa[g][threadIdx.x]=pa; sb[g][threadIdx.x]=pb;
      float na = pa*ca;
      float nb = ca*pb + cb2;
      pa=na; pb=nb;
    }
  }
  __syncthreads();
  float h = sb[seg][chl];
  for (int cb=c0; cb<c0+SEG; cb+=8){
    float av[8], bv[8];
#pragma unroll
    for (int k=0;k<8;k++){ av[k]=aggA[(cb+k)*CH+ch]; bv[k]=aggB[(cb+k)*CH+ch]; }
#pragma unroll
    for (int k=0;k<8;k++){ carry[(cb+k)*CH+ch]=h; h = av[k]*h + bv[k]; }
  }
}

// =================================================================================
// k_back: fused pass2 scan + z-gate + out-proj + residual -> bf16 padded layout.
// =================================================================================
template<int DIM, int DI, int DTR, int RES>
__global__ __launch_bounds__(256) void k_back(
    const float* __restrict__ xcg, const float* __restrict__ zg,
    const float* __restrict__ dtpg, const float* __restrict__ Bg, const float* __restrict__ Cg,
    const float* __restrict__ dtw, const float* __restrict__ dtb,
    const float* __restrict__ Alog, const float* __restrict__ Dp,
    const float* __restrict__ carry,
    const float* __restrict__ ow,
    const float* __restrict__ r0src, const float* __restrict__ r1src,
    const float* __restrict__ bstats, const float* __restrict__ bg, const float* __restrict__ bbp,
    unsigned short* __restrict__ rp)
{
  constexpr int TCH = 48;
  constexpr int NSH = 256/DI;
  constexpr int SPB = 16/NSH;
  constexpr int ROWS = DTR + 32;
  constexpr int O_SXC = 0;               // DI*49
  constexpr int O_SDT = O_SXC + DI*49;   // DI*49
  constexpr int O_SB  = O_SDT + DI*49;   // 16*49
  constexpr int O_SC  = O_SB + 16*49;    // 16*49
  constexpr int O_SY  = O_SC + 16*49;    // DI*49
  constexpr int O_DTP = O_SY + DI*49;    // DTR*48
  constexpr int SMEM  = O_DTP + DTR*48 + 64;
  __shared__ float sm[SMEM];
  const int tid   = threadIdx.x;
  const int chunk = blockIdx.x;
  const int t0    = chunk*TCH;

  // ---- load xc / B / C / dtp (float4 global, scalar LDS scatter)
  for (int idx = tid; idx < DI*12; idx += 256){
    int d = idx / 12, q = idx - d*12;
    float4 v = *reinterpret_cast<const float4*>(xcg + d*L_TOT + t0 + q*4);
    sm[O_SXC + d*49 + q*4+0] = v.x; sm[O_SXC + d*49 + q*4+1] = v.y;
    sm[O_SXC + d*49 + q*4+2] = v.z; sm[O_SXC + d*49 + q*4+3] = v.w;
  }
  for (int idx = tid; idx < ROWS*12; idx += 256){
    int r = idx / 12, q = idx - r*12;
    const float* src; float* dst;
    if (r < DTR)        { src = dtpg + r*L_TOT + t0 + q*4;         dst = &sm[O_DTP + r*48 + q*4]; }
    else if (r < DTR+16){ src = Bg + (r-DTR)*L_TOT + t0 + q*4;     dst = &sm[O_SB + (r-DTR)*49 + q*4]; }
    else                { src = Cg + (r-DTR-16)*L_TOT + t0 + q*4;  dst = &sm[O_SC + (r-DTR-16)*49 + q*4]; }
    float4 v = *reinterpret_cast<const float4*>(src);
    dst[0] = v.x; dst[1] = v.y; dst[2] = v.z; dst[3] = v.w;
  }
  __syncthreads();
  // ---- dt = softplus(dtb + dtw*dtp)
  for (int idx = tid; idx < DI*48; idx += 256){
    int d = idx / 48, j = idx - d*48;
    float pre = dtb[d] + dtw[d*DTR]*sm[O_DTP + j];
    if (DTR > 1) pre += dtw[d*DTR + DTR-1]*sm[O_DTP + 48 + j];
    sm[O_SDT + d*49 + j] = fsoftplus(pre);
  }
  __syncthreads();

  // ---- pass2 scan: h update + y = sum_s h*C + xc*D -> SY
  {
    const int d  = tid / NSH;
    const int sh = tid - d*NSH;
    float Av[SPB], h[SPB];
#pragma unroll
    for (int j = 0; j < SPB; j++){
      Av[j] = -__expf(Alog[d*16 + sh*SPB + j]);
      h[j]  = carry[chunk*(DI*16) + tid*SPB + j];
    }
    const float Dv = Dp[d];
    for (int t = 0; t < TCH; t++){
      float dtv = sm[O_SDT + d*49 + t];
      float xcv = sm[O_SXC + d*49 + t];
      float bb2 = dtv*xcv;
      float p = 0.f;
#pragma unroll
      for (int j = 0; j < SPB; j++){
        float a2 = __expf(dtv*Av[j]);
        h[j] = a2*h[j] + bb2*sm[O_SB + (sh*SPB+j)*49 + t];
        p += h[j]*sm[O_SC + (sh*SPB+j)*49 + t];
      }
#pragma unroll
      for (int o = 1; o < NSH; o <<= 1) p += __shfl_xor(p, o);
      if (sh == 0) sm[O_SY + d*49 + t] = p + xcv*Dv;
    }
  }
  __syncthreads();
  // ---- gate: y *= silu(z)   (z streamed from global, never staged)
  for (int idx = tid; idx < DI*12; idx += 256){
    int d = idx / 12, q = idx - d*12;
    float4 zv = *reinterpret_cast<const float4*>(zg + d*L_TOT + t0 + q*4);
    sm[O_SY + d*49 + q*4+0] *= zv.x*fsigmoid(zv.x);
    sm[O_SY + d*49 + q*4+1] *= zv.y*fsigmoid(zv.y);
    sm[O_SY + d*49 + q*4+2] *= zv.z*fsigmoid(zv.z);
    sm[O_SY + d*49 + q*4+3] *= zv.w*fsigmoid(zv.w);
  }
  __syncthreads();

  // ---- out-proj + residual -> padded bf16 conv input
  {
    const int col = tid & 63;
    const int r0w = __builtin_amdgcn_readfirstlane(tid >> 6);
    constexpr int NO = DIM/4;
    float acc[NO];
#pragma unroll
    for (int rr = 0; rr < NO; rr++) acc[rr] = 0.f;
    for (int db = 0; db < DI; db += 16){
      float ycol[16];
#pragma unroll
      for (int k = 0; k < 16; k++) ycol[k] = sm[O_SY + (db+k)*49 + col];
#pragma unroll
      for (int rr = 0; rr < NO; rr++){
        int r = r0w + rr*4;
        float a2 = 0.f;
#pragma unroll
        for (int k = 0; k < 16; k++) a2 += ycol[k]*ow[r*DI + db + k];
        acc[rr] += a2;
      }
    }
    if (col < 48){
      const int t  = t0 + col;
      const int zz = chunk / 48, yy = chunk - zz*48;     // 48 cols = one (zz,yy) row
      const int pb = (zz+1)*2500 + (yy+1)*50 + (col+1);
#pragma unroll
      for (int rr = 0; rr < NO; rr++){
        int r = r0w + rr*4;
        float res;
        if (RES == 0){
          res = (r < 16) ? r0src[r*L_TOT + t] : r1src[(r-16)*L_TOT + t];
        } else {
          float bm = bstats[2*r]*(1.f/L_TOT);
          float bv = bstats[2*r+1]*(1.f/L_TOT) - bm*bm;
          res = (r0src[r*L_TOT + t] - bm)*rsqrtf(bv+BN_EPS)*bg[r] + bbp[r];
        }
        rp[r*PCH + pb] = f2bf(acc[rr] + res);
      }
    }
  }
}

// ---------------- conv3d via MFMA implicit GEMM + fused BN partial sums -----------
template<int IC>
__global__ __launch_bounds__(256) void k_conv_mfma(const unsigned short* __restrict__ bin,
                         const unsigned short* __restrict__ wA,
                         const float* __restrict__ bias, float* __restrict__ out,
                         float* __restrict__ stats) {
  constexpr int NKB = (IC==32) ? 27 : 14;
  __shared__ float sred[32];
  if (threadIdx.x < 32) sred[threadIdx.x] = 0.f;
  __syncthreads();
  const int lane = threadIdx.x & 63;
  const int n = lane & 15, quad = lane >> 4;
  const int tile = blockIdx.x*4 + (threadIdx.x >> 6);
  const int t = tile*16 + n;
  int zz = t / 2304;
  int r2 = t - zz*2304;
  int yy = r2 / 48;
  int xx = r2 - yy*48;
  int pb = (zz+1)*2500 + (yy+1)*50 + (xx+1);
  const unsigned short* bp[8];
#pragma unroll
  for (int j=0;j<8;j++){
    int e = quad*8 + j;
    int ic = (IC==32) ? e : (e & 15);
    bp[j] = bin + ic*PCH + pb;
  }
  const int rq = (IC==32) ? 0 : (quad >> 1);
  f32x4 acc = {0.f, 0.f, 0.f, 0.f};
#pragma unroll
  for (int kb=0; kb<NKB; kb++){
    bf16x8 af = *reinterpret_cast<const bf16x8*>(wA + (size_t)((kb*4+quad)*16 + n)*8);
    int off;
    if (IC==32) off = off3c(kb);
    else        off = rq ? off3c(2*kb+1) : off3c(2*kb);
    bf16x8 bf;
#pragma unroll
    for (int j=0;j<8;j++) bf[j] = (short)bp[j][off];
    acc = __builtin_amdgcn_mfma_f32_16x16x32_bf16(af, bf, acc, 0, 0, 0);
  }
  float vs[4];
#pragma unroll
  for (int reg=0; reg<4; reg++){
    int m = quad*4 + reg;
    float v = acc[reg] + bias[m];
    out[m*L_TOT + t] = v;
    vs[reg] = v;
  }
#pragma unroll
  for (int reg=0; reg<4; reg++){
    float a = vs[reg], b2 = vs[reg]*vs[reg];
#pragma unroll
    for (int o=1; o<16; o<<=1){ a += __shfl_xor(a,o); b2 += __shfl_xor(b2,o); }
    if (n == 0){
      atomicAdd(&sred[quad*4+reg], a);
      atomicAdd(&sred[16 + quad*4+reg], b2);
    }
  }
  __syncthreads();
  if (threadIdx.x < 16){
    atomicAdd(&stats[2*threadIdx.x],   sred[threadIdx.x]);
    atomicAdd(&stats[2*threadIdx.x+1], sred[16+threadIdx.x]);
  }
}

// ---------------- BN normalize, float4 --------------------------------------------
__global__ void k_bn_norm4(const float* __restrict__ raw, const float* __restrict__ stats,
                           const float* __restrict__ g, const float* __restrict__ b,
                           float* __restrict__ out) {
  int i = blockIdx.x*256 + threadIdx.x;         // over 16*L_TOT/4
  int c = i / (L_TOT/4);
  int tq = i - c*(L_TOT/4);
  float m = stats[2*c]*(1.f/L_TOT);
  float v = stats[2*c+1]*(1.f/L_TOT) - m*m;
  float sc = rsqrtf(v+BN_EPS)*g[c];
  float bs = b[c] - m*sc;
  float4 x = *reinterpret_cast<const float4*>(raw + c*L_TOT + tq*4);
  float4 o = make_float4(x.x*sc+bs, x.y*sc+bs, x.z*sc+bs, x.w*sc+bs);
  *reinterpret_cast<float4*>(out + c*L_TOT + tq*4) = o;
}

// =================================================================================
extern "C" void kernel_launch(void* const* d_in, const int* in_sizes, int n_in,
                              void* d_out, int out_size, void* d_ws, size_t ws_size,
                              hipStream_t stream) {
  const float* l        = (const float*)d_in[0];
  const float* s        = (const float*)d_in[1];
  const float* m1_ln_w  = (const float*)d_in[2];
  const float* m1_ln_b  = (const float*)d_in[3];
  const float* m1_in_w  = (const float*)d_in[4];
  const float* m1_cw    = (const float*)d_in[5];
  const float* m1_cb    = (const float*)d_in[6];
  const float* m1_xp_w  = (const float*)d_in[7];
  const float* m1_dt_w  = (const float*)d_in[8];
  const float* m1_dt_b  = (const float*)d_in[9];
  const float* m1_Alog  = (const float*)d_in[10];
  const float* m1_D     = (const float*)d_in[11];
  const float* m1_out_w = (const float*)d_in[12];
  const float* m2_ln_w  = (const float*)d_in[13];
  const float* m2_ln_b  = (const float*)d_in[14];
  const float* m2_in_w  = (const float*)d_in[15];
  const float* m2_cw    = (const float*)d_in[16];
  const float* m2_cb    = (const float*)d_in[17];
  const float* m2_xp_w  = (const float*)d_in[18];
  const float* m2_dt_w  = (const float*)d_in[19];
  const float* m2_dt_b  = (const float*)d_in[20];
  const float* m2_Alog  = (const float*)d_in[21];
  const float* m2_D     = (const float*)d_in[22];
  const float* m2_out_w = (const float*)d_in[23];
  const float* c1_w     = (const float*)d_in[24];
  const float* c1_b     = (const float*)d_in[25];
  const float* bn1_g    = (const float*)d_in[26];
  const float* bn1_b    = (const float*)d_in[27];
  const float* c2_w     = (const float*)d_in[28];
  const float* c2_b     = (const float*)d_in[29];
  const float* bn2_g    = (const float*)d_in[30];
  const float* bn2_b    = (const float*)d_in[31];

  float* ws = (float*)d_ws;
  const size_t L = L_TOT;
  float* xc1      = ws;               // 64L
  float* z1       = ws + 64*L;        // 64L
  float* B1       = ws + 128*L;       // 16L   (reused by stage 2)
  float* C1       = ws + 144*L;       // 16L   (reused by stage 2)
  float* dtp1     = ws + 160*L;       // 2L    (reused by stage 2)
  float* conv1raw = ws + 162*L;       // 16L
  float* xc2      = ws + 178*L;       // 32L
  float* z2       = ws + 210*L;       // 32L
  float* conv2raw = ws + 242*L;       // 16L
  float* aggA     = ws + 258*L;       // 786432
  float* aggB     = aggA + 786432;
  float* carry    = aggB + 786432;    // ends at 322L
  float* stats1   = ws + 322*L;       // 32
  float* stats2   = stats1 + 32;      // 32
  unsigned short* bfin = (unsigned short*)(ws + 323*L);   // 32ch * PCH bf16
  unsigned short* wA1  = (unsigned short*)(ws + 343*L);   // 13824
  unsigned short* wA2  = wA1 + 13824;                     // 7168

  // ================= stage 1: mamba(dim=32, di=64) + conv1 + bn1(stats) ==========
  // k_front<...,SETUP=true> also performs the old k_setup work (weight pack, bfin
  // halo zero, stats zero) - all consumed only by later kernels in stream order.
  k_front<32,64,2,false,true><<<768,256,0,stream>>>(l, s, stats1, bn1_g, bn1_b,
      m1_ln_w, m1_ln_b, m1_in_w, m1_cw, m1_cb, m1_xp_w, m1_dt_w, m1_dt_b, m1_Alog,
      xc1, z1, dtp1, B1, C1, aggA, aggB,
      c1_w, wA1, c2_w, wA2, stats1, (float*)bfin);
  k_carry<768><<<64,256,0,stream>>>(aggA, aggB, carry, 1024);
  k_back<32,64,2,0><<<768,256,0,stream>>>(xc1, z1, dtp1, B1, C1,
      m1_dt_w, m1_dt_b, m1_Alog, m1_D, carry, m1_out_w, l, s,
      stats1, bn1_g, bn1_b, bfin);
  k_conv_mfma<32><<<576,256,0,stream>>>(bfin, wA1, c1_b, conv1raw, stats1);

  // ================= stage 2: mamba(dim=16, di=32) + conv2 + bn2 =================
  k_front<16,32,1,true,false><<<768,256,0,stream>>>(conv1raw, conv1raw, stats1, bn1_g, bn1_b,
      m2_ln_w, m2_ln_b, m2_in_w, m2_cw, m2_cb, m2_xp_w, m2_dt_w, m2_dt_b, m2_Alog,
      xc2, z2, dtp1, B1, C1, aggA, aggB,
      nullptr, nullptr, nullptr, nullptr, nullptr, nullptr);
  k_carry<768><<<32,256,0,stream>>>(aggA, aggB, carry, 512);
  k_back<16,32,1,1><<<768,256,0,stream>>>(xc2, z2, dtp1, B1, C1,
      m2_dt_w, m2_dt_b, m2_Alog, m2_D, carry, m2_out_w, conv1raw, conv1raw,
      stats1, bn1_g, bn1_b, bfin);
  k_conv_mfma<16><<<576,256,0,stream>>>(bfin, wA2, c2_b, conv2raw, stats2);
  k_bn_norm4<<<576,256,0,stream>>>(conv2raw, stats2, bn2_g, bn2_b, (float*)d_out);
}